// Round 6
// baseline (787.485 us; speedup 1.0000x reference)
//
#include <hip/hip_runtime.h>
#include <hip/hip_bf16.h>

#define LL 128
#define BB 32
#define EE 128
#define HH 256
#define NHH 8
#define G3 768   // 3*H
#define IN0 130
#define ETA 100
#define F1 168
#define CLSIN 2304  // 8*256 + 256

typedef _Float16 half_t;
typedef __attribute__((ext_vector_type(2))) _Float16 half2v;

#if defined(__has_builtin)
#if __has_builtin(__builtin_amdgcn_fdot2)
#define HAVE_FDOT2 1
#endif
#endif

__device__ __forceinline__ float fdot2f(half2v a, half2v b, float c) {
#ifdef HAVE_FDOT2
  return __builtin_amdgcn_fdot2(a, b, c, false);
#else
  return c + (float)a.x * (float)b.x + (float)a.y * (float)b.y;
#endif
}
__device__ __forceinline__ float fdot2u(unsigned int a, unsigned int b, float c) {
  return fdot2f(__builtin_bit_cast(half2v, a), __builtin_bit_cast(half2v, b), c);
}

// LDS-only barrier: skip the compiler's vmcnt(0) drain (no cross-thread
// global-memory dependencies at our barriers).
#define BARRIER_LDS() __asm__ volatile("s_waitcnt lgkmcnt(0)\n\ts_barrier" ::: "memory")

__device__ __forceinline__ float sigmoidf_(float x) { return 1.0f / (1.0f + __expf(-x)); }
__device__ __forceinline__ float tanhf_(float x) { return 1.0f - 2.0f / (__expf(2.0f * x) + 1.0f); }

// ---------------------------------------------------------------------------
// prep: weight repack fp32 -> f16 (weights ~N(0,0.05^2): f16 rel err 5e-4)
// ---------------------------------------------------------------------------
__global__ void prep_kernel(
    const float* __restrict__ Wa0, const float* __restrict__ Wih0,
    const float* __restrict__ Wih1, const float* __restrict__ Whh0,
    const float* __restrict__ Whh1,
    half_t* __restrict__ Wa0Ta, half_t* __restrict__ Wa0Tb,
    half2v* __restrict__ Wih0T2, half2v* __restrict__ Wih1T2,
    half_t* __restrict__ Whh0h, half_t* __restrict__ Whh1h)
{
  int idx = blockIdx.x * blockDim.x + threadIdx.x;
  const int n1 = 16384, n2 = 16384, n3 = 65 * 768, n4 = 128 * 768, n5 = 196608;
  if (idx < n1) {
    int d = idx >> 7, k = idx & 127;
    Wa0Ta[idx] = (half_t)Wa0[k * 256 + d];
  } else if ((idx -= n1) < n2) {
    int d = idx >> 7, k = idx & 127;
    Wa0Tb[idx] = (half_t)Wa0[k * 256 + 128 + d];
  } else if ((idx -= n2) < n3) {
    int d2 = idx / 768, r = idx % 768;
    half2v w; w.x = (half_t)Wih0[r * IN0 + 2 * d2]; w.y = (half_t)Wih0[r * IN0 + 2 * d2 + 1];
    Wih0T2[idx] = w;
  } else if ((idx -= n3) < n4) {
    int d2 = idx / 768, r = idx % 768;
    half2v w; w.x = (half_t)Wih1[r * HH + 2 * d2]; w.y = (half_t)Wih1[r * HH + 2 * d2 + 1];
    Wih1T2[idx] = w;
  } else if ((idx -= n4) < n5) {
    Whh0h[idx] = (half_t)Whh0[idx];
  } else if ((idx -= n5) < n5) {
    Whh1h[idx] = (half_t)Whh1[idx];
  }
}

// ---------------------------------------------------------------------------
// embed gather + U/V factors of the pairwise attention
// ---------------------------------------------------------------------------
__global__ void embed_uv_kernel(
    const int* __restrict__ node,             // [L*B]
    const float* __restrict__ table,          // [20001][128]
    const half_t* __restrict__ Wa0Ta,         // [128 d][128 k]
    const half_t* __restrict__ Wa0Tb,
    const float* __restrict__ ba0,            // [128]
    half2v* __restrict__ e_h2,                // [L*B][64]
    float* __restrict__ U,
    float* __restrict__ V)
{
  int lb = blockIdx.x;
  int k = threadIdx.x;  // 128
  __shared__ float es[EE];
  int n = node[lb];
  float ev = table[(size_t)n * EE + k];
  es[k] = ev;
  __syncthreads();
  if (k < 64) {
    half2v p; p.x = (half_t)es[2 * k]; p.y = (half_t)es[2 * k + 1];
    e_h2[(size_t)lb * 64 + k] = p;
  }
  float u = 0.f, v = ba0[k];
  #pragma unroll 8
  for (int d = 0; d < EE; ++d) {
    float x = es[d];
    u += (float)Wa0Ta[d * EE + k] * x;
    v += (float)Wa0Tb[d * EE + k] * x;
  }
  U[(size_t)lb * EE + k] = u;
  V[(size_t)lb * EE + k] = v;
}

// ---------------------------------------------------------------------------
// w_pre[i,b,h] = sum_j sum_k Wa1[h,k] * relu(U[j,b,k]+V[i,b,k]) + L*ba1[h]
// ---------------------------------------------------------------------------
__global__ __launch_bounds__(128) void attn_w_kernel(
    const float* __restrict__ U, const float* __restrict__ V,
    const float* __restrict__ Wa1,  // [8][128]
    const float* __restrict__ ba1,  // [8]
    float* __restrict__ wpre)       // [L][B][8]
{
  int ig = blockIdx.x >> 5;
  int b = blockIdx.x & 31;
  int i0 = ig * 4;
  int k = threadIdx.x;  // 128
  float vk[4];
  #pragma unroll
  for (int ii = 0; ii < 4; ++ii) vk[ii] = V[((size_t)(i0 + ii) * BB + b) * EE + k];
  float wa[NHH], acc[4][NHH];
  #pragma unroll
  for (int h = 0; h < NHH; ++h) wa[h] = Wa1[h * EE + k];
  #pragma unroll
  for (int ii = 0; ii < 4; ++ii)
    #pragma unroll
    for (int h = 0; h < NHH; ++h) acc[ii][h] = 0.f;
  for (int j = 0; j < LL; ++j) {
    float u = U[((size_t)j * BB + b) * EE + k];
    #pragma unroll
    for (int ii = 0; ii < 4; ++ii) {
      float tv = fmaxf(u + vk[ii], 0.f);
      #pragma unroll
      for (int h = 0; h < NHH; ++h) acc[ii][h] += wa[h] * tv;
    }
  }
  __shared__ float part[2][32];
  int wave = k >> 6, lane = k & 63;
  #pragma unroll
  for (int ii = 0; ii < 4; ++ii)
    #pragma unroll
    for (int h = 0; h < NHH; ++h) {
      float a = acc[ii][h];
      #pragma unroll
      for (int off = 32; off > 0; off >>= 1) a += __shfl_xor(a, off, 64);
      if (lane == 0) part[wave][ii * 8 + h] = a;
    }
  __syncthreads();
  if (k < 32) {
    int ii = k >> 3, h = k & 7;
    float w = part[0][k] + part[1][k] + (float)LL * ba1[h];
    wpre[((size_t)(i0 + ii) * BB + b) * NHH + h] = w;
  }
}

// softmax over l of (w * mask): masked entries become 0 and STAY in the softmax
__global__ void attn_softmax_kernel(
    const float* __restrict__ wpre, const int* __restrict__ slen,
    float* __restrict__ wsoft)
{
  int b = blockIdx.x >> 3;
  int h = blockIdx.x & 7;
  int l = threadIdx.x;  // 128
  int len = slen[b];
  float x = wpre[((size_t)l * BB + b) * NHH + h];
  float xv = (l < len) ? x : 0.f;
  float m = xv;
  #pragma unroll
  for (int off = 32; off > 0; off >>= 1) m = fmaxf(m, __shfl_xor(m, off, 64));
  __shared__ float sm[2], ss[2];
  int wave = l >> 6;
  if ((l & 63) == 0) sm[wave] = m;
  __syncthreads();
  m = fmaxf(sm[0], sm[1]);
  float e = __expf(xv - m);
  float s = e;
  #pragma unroll
  for (int off = 32; off > 0; off >>= 1) s += __shfl_xor(s, off, 64);
  if ((l & 63) == 0) ss[wave] = s;
  __syncthreads();
  s = ss[0] + ss[1];
  wsoft[((size_t)l * BB + b) * NHH + h] = e / s;
}

// ---------------------------------------------------------------------------
// gi0: [e, ts] @ Wih0.T + bih0, 8 lb per block, v_dot2 on packed pairs
// ---------------------------------------------------------------------------
__global__ __launch_bounds__(256) void gi0_kernel(
    const half2v* __restrict__ e_h2, const float* __restrict__ ts,
    const half2v* __restrict__ W2,   // [65][768]
    const float* __restrict__ bih,
    float* __restrict__ gi)
{
  int lb0 = blockIdx.x * 8;
  int tid = threadIdx.x;  // 256
  __shared__ half2v xs2[8][66];
  for (int idx = tid; idx < 512; idx += 256) {
    int q = idx >> 6, d2 = idx & 63;
    xs2[q][d2] = e_h2[(size_t)(lb0 + q) * 64 + d2];
  }
  if (tid < 8) {
    half2v t2; t2.x = (half_t)ts[(lb0 + tid) * 2]; t2.y = (half_t)ts[(lb0 + tid) * 2 + 1];
    xs2[tid][64] = t2;
  }
  __syncthreads();
  float acc[8][3];
  #pragma unroll
  for (int q = 0; q < 8; ++q) { acc[q][0] = 0.f; acc[q][1] = 0.f; acc[q][2] = 0.f; }
  for (int d2 = 0; d2 < 65; ++d2) {
    half2v w0 = W2[d2 * 768 + tid];
    half2v w1 = W2[d2 * 768 + 256 + tid];
    half2v w2 = W2[d2 * 768 + 512 + tid];
    #pragma unroll
    for (int q = 0; q < 8; ++q) {
      half2v x = xs2[q][d2];
      acc[q][0] = fdot2f(w0, x, acc[q][0]);
      acc[q][1] = fdot2f(w1, x, acc[q][1]);
      acc[q][2] = fdot2f(w2, x, acc[q][2]);
    }
  }
  float b0 = bih[tid], b1 = bih[256 + tid], b2 = bih[512 + tid];
  #pragma unroll
  for (int q = 0; q < 8; ++q) {
    float* gp = gi + (size_t)(lb0 + q) * G3;
    gp[tid] = acc[q][0] + b0; gp[256 + tid] = acc[q][1] + b1; gp[512 + tid] = acc[q][2] + b2;
  }
}

// ---------------------------------------------------------------------------
// gi1: out0 @ Wih1.T + bih1, 8 lb per block
// ---------------------------------------------------------------------------
__global__ __launch_bounds__(256) void gi1_kernel(
    const float* __restrict__ out0,  // [L*B][256]
    const half2v* __restrict__ W2,   // [128][768]
    const float* __restrict__ bih,
    float* __restrict__ gi)
{
  int lb0 = blockIdx.x * 8;
  int tid = threadIdx.x;  // 256
  __shared__ half2v xs2[8][128];
  for (int idx = tid; idx < 1024; idx += 256) {
    int q = idx >> 7, d2 = idx & 127;
    float2 v = ((const float2*)(out0 + (size_t)(lb0 + q) * HH))[d2];
    half2v x; x.x = (half_t)v.x; x.y = (half_t)v.y;
    xs2[q][d2] = x;
  }
  __syncthreads();
  float acc[8][3];
  #pragma unroll
  for (int q = 0; q < 8; ++q) { acc[q][0] = 0.f; acc[q][1] = 0.f; acc[q][2] = 0.f; }
  for (int d2 = 0; d2 < 128; ++d2) {
    half2v w0 = W2[d2 * 768 + tid];
    half2v w1 = W2[d2 * 768 + 256 + tid];
    half2v w2 = W2[d2 * 768 + 512 + tid];
    #pragma unroll
    for (int q = 0; q < 8; ++q) {
      half2v x = xs2[q][d2];
      acc[q][0] = fdot2f(w0, x, acc[q][0]);
      acc[q][1] = fdot2f(w1, x, acc[q][1]);
      acc[q][2] = fdot2f(w2, x, acc[q][2]);
    }
  }
  float b0 = bih[tid], b1 = bih[256 + tid], b2 = bih[512 + tid];
  #pragma unroll
  for (int q = 0; q < 8; ++q) {
    float* gp = gi + (size_t)(lb0 + q) * G3;
    gp[tid] = acc[q][0] + b0; gp[256 + tid] = acc[q][1] + b1; gp[512 + tid] = acc[q][2] + b2;
  }
}

// ---------------------------------------------------------------------------
// GRU scan: 256 threads/block (4 waves = 1 wave/SIMD, 1 block/CU) so
// __launch_bounds__(256,1) unlocks the 512-VGPR/wave budget. Thread
// (g = tid>>1, s = tid&1) holds rows 6g..6g+5 over k-half [128s,128s+128)
// = 96 uint4 = 384 weight VGPRs, loaded once, used via constant indices —
// no pins, just slack for the allocator. Phase 1: 384 v_dot2 + 16 b128
// h-reads (2-way broadcast = free). Phase 2: stride-3 partials (conflict-
// free), gates, h/out writes.
// ---------------------------------------------------------------------------
__global__ __launch_bounds__(256, 1) void gru_scan_kernel(
    const half_t* __restrict__ Whhh,         // [768][256] f16
    const float* __restrict__ bhh,           // [768]
    const float* __restrict__ gi,            // [L][B][768]
    const int* __restrict__ slen,            // [B]
    float* __restrict__ out,                 // [L][B][256]
    float* __restrict__ hT)                  // [B][256]
{
  const int b = blockIdx.x;
  const int tid = threadIdx.x;  // 256
  const int s = tid & 1;
  const int g = tid >> 1;
  __shared__ __align__(16) uint4 h4[2][17];  // 2 k-chunks x (16 data + 1 pad)
  __shared__ float p3[768 * 3];              // [row]*3 + s partials

  uint4 w[96];
  #pragma unroll
  for (int r = 0; r < 6; ++r) {
    const uint4* wp = (const uint4*)(Whhh + (size_t)(6 * g + r) * HH + 128 * s);
    #pragma unroll
    for (int j = 0; j < 16; ++j) w[r * 16 + j] = wp[j];
  }

  const int len = slen[b];
  float bhr = bhh[tid], bhz = bhh[HH + tid], bhn = bhh[2 * HH + tid];
  float hold = 0.f;
  if (tid < 34) { uint4 z; z.x = z.y = z.z = z.w = 0u; ((uint4*)h4)[tid] = z; }
  __syncthreads();

  const float* gib = gi + (size_t)b * G3;
  float* outb = out + (size_t)b * HH;

  #pragma unroll 1
  for (int t = 0; t < LL; ++t) {
    // gi loads issued up front; latency hides under the dot phase
    const float* gp = gib + (size_t)t * (BB * G3);
    float g0 = gp[tid], g1 = gp[HH + tid], g2 = gp[2 * HH + tid];
    float acc[6] = {0.f, 0.f, 0.f, 0.f, 0.f, 0.f};
    #pragma unroll
    for (int c = 0; c < 16; ++c) {
      uint4 hv = h4[s][c];
      #pragma unroll
      for (int r = 0; r < 6; ++r) {
        uint4 wv = w[r * 16 + c];
        acc[r] = fdot2u(wv.x, hv.x, acc[r]);
        acc[r] = fdot2u(wv.y, hv.y, acc[r]);
        acc[r] = fdot2u(wv.z, hv.z, acc[r]);
        acc[r] = fdot2u(wv.w, hv.w, acc[r]);
      }
    }
    #pragma unroll
    for (int r = 0; r < 6; ++r)
      p3[(6 * g + r) * 3 + s] = acc[r];
    BARRIER_LDS();
    {
      float srz = p3[tid * 3] + p3[tid * 3 + 1];
      float sz  = p3[(HH + tid) * 3] + p3[(HH + tid) * 3 + 1];
      float sn  = p3[(2 * HH + tid) * 3] + p3[(2 * HH + tid) * 3 + 1];
      float r_ = sigmoidf_(g0 + srz + bhr);
      float z_ = sigmoidf_(g1 + sz + bhz);
      float n_ = tanhf_(g2 + r_ * (sn + bhn));
      float hnew = (1.f - z_) * n_ + z_ * hold;
      bool valid = t < len;
      hold = valid ? hnew : hold;
      ((half_t*)(h4[tid >> 7]))[tid & 127] = (half_t)hold;
      outb[(size_t)t * (BB * HH) + tid] = valid ? hnew : 0.f;
    }
    BARRIER_LDS();
  }
  hT[(size_t)b * HH + tid] = hold;
}

// ---------------------------------------------------------------------------
// ctx[b, h*256+d] = sum_l wsoft[l,b,h] * out1[l,b,d]
// ---------------------------------------------------------------------------
__global__ void ctx_kernel(
    const float* __restrict__ wsoft, const float* __restrict__ out1,
    float* __restrict__ ctx)
{
  int b = blockIdx.x >> 3, h = blockIdx.x & 7;
  int d = threadIdx.x;  // 256
  float acc = 0.f;
  for (int l = 0; l < LL; ++l) {
    float w = wsoft[((size_t)l * BB + b) * NHH + h];
    acc += w * out1[((size_t)l * BB + b) * HH + d];
  }
  ctx[(size_t)b * (NHH * HH) + h * HH + d] = acc;
}

// ---------------------------------------------------------------------------
// final MLP: z = selu([ctx, hT] @ Wf0.T + bf0); logits = z @ Wf1.T + bf1;
// out = log_softmax(logits)
// ---------------------------------------------------------------------------
__global__ __launch_bounds__(512) void final_kernel(
    const float* __restrict__ ctx, const float* __restrict__ hT,
    const float* __restrict__ Wf0,   // [168][2304]
    const float* __restrict__ bf0,
    const float* __restrict__ Wf1,   // [100][168]
    const float* __restrict__ bf1,
    float* __restrict__ outp)        // [B][100]
{
  int b = blockIdx.x;
  int tid = threadIdx.x;
  int wave = tid >> 6, lane = tid & 63;
  __shared__ float4 xs4[CLSIN / 4];
  __shared__ float zs[F1];
  __shared__ float ls[ETA];
  float* xs = (float*)xs4;
  for (int i = tid; i < NHH * HH; i += 512) xs[i] = ctx[(size_t)b * (NHH * HH) + i];
  if (tid < HH) xs[NHH * HH + tid] = hT[(size_t)b * HH + tid];
  __syncthreads();
  for (int r = wave; r < F1; r += 8) {
    const float4* wp = (const float4*)(Wf0 + (size_t)r * CLSIN);
    float acc = 0.f;
    #pragma unroll
    for (int i = 0; i < CLSIN / 4 / 64; ++i) {  // 9
      float4 w = wp[lane + 64 * i];
      float4 x = xs4[lane + 64 * i];
      acc += w.x * x.x + w.y * x.y + w.z * x.z + w.w * x.w;
    }
    #pragma unroll
    for (int off = 32; off > 0; off >>= 1) acc += __shfl_xor(acc, off, 64);
    if (lane == 0) {
      float x = acc + bf0[r];
      const float alpha = 1.6732632423543772f, scale = 1.0507009873554805f;
      zs[r] = scale * (x > 0.f ? x : alpha * (__expf(x) - 1.f));
    }
  }
  __syncthreads();
  for (int r = wave; r < ETA; r += 8) {
    float acc = 0.f;
    for (int k = lane; k < F1; k += 64) acc += Wf1[r * F1 + k] * zs[k];
    #pragma unroll
    for (int off = 32; off > 0; off >>= 1) acc += __shfl_xor(acc, off, 64);
    if (lane == 0) ls[r] = acc + bf1[r];
  }
  __syncthreads();
  if (wave == 0) {
    float v0 = (lane < ETA) ? ls[lane] : -1e30f;
    float v1 = (lane + 64 < ETA) ? ls[lane + 64] : -1e30f;
    float m = fmaxf(v0, v1);
    #pragma unroll
    for (int off = 32; off > 0; off >>= 1) m = fmaxf(m, __shfl_xor(m, off, 64));
    float s = __expf(v0 - m) + __expf(v1 - m);
    #pragma unroll
    for (int off = 32; off > 0; off >>= 1) s += __shfl_xor(s, off, 64);
    float lse = m + __logf(s);
    if (lane < ETA) outp[(size_t)b * ETA + lane] = v0 - lse;
    if (lane + 64 < ETA) outp[(size_t)b * ETA + lane + 64] = v1 - lse;
  }
}

extern "C" void kernel_launch(void* const* d_in, const int* in_sizes, int n_in,
                              void* d_out, int out_size, void* d_ws, size_t ws_size,
                              hipStream_t stream) {
  const int*   node  = (const int*)d_in[0];
  const float* ts    = (const float*)d_in[1];
  const int*   slen  = (const int*)d_in[2];
  const float* table = (const float*)d_in[3];
  const float* Wih0  = (const float*)d_in[4];
  const float* Whh0  = (const float*)d_in[5];
  const float* bih0  = (const float*)d_in[6];
  const float* bhh0  = (const float*)d_in[7];
  const float* Wih1  = (const float*)d_in[8];
  const float* Whh1  = (const float*)d_in[9];
  const float* bih1  = (const float*)d_in[10];
  const float* bhh1  = (const float*)d_in[11];
  const float* Wa0   = (const float*)d_in[12];
  const float* ba0   = (const float*)d_in[13];
  const float* Wa1   = (const float*)d_in[14];
  const float* ba1   = (const float*)d_in[15];
  const float* Wf0   = (const float*)d_in[16];
  const float* bf0   = (const float*)d_in[17];
  const float* Wf1   = (const float*)d_in[18];
  const float* bf1   = (const float*)d_in[19];

  char* ws = (char*)d_ws;
  size_t off = 0;
  auto alloc = [&](size_t n) { void* p = (void*)(ws + off); off += (n + 255) & ~(size_t)255; return p; };

  half2v* e_h2 = (half2v*)alloc((size_t)LL * BB * 64 * 4);
  float* U     = (float*)alloc((size_t)LL * BB * EE * 4);
  float* V     = (float*)alloc((size_t)LL * BB * EE * 4);
  float* gi    = (float*)alloc((size_t)LL * BB * G3 * 4);   // reused for both layers
  float* out0  = (float*)alloc((size_t)LL * BB * HH * 4);
  float* out1  = (float*)alloc((size_t)LL * BB * HH * 4);
  float* hTb   = (float*)alloc((size_t)BB * HH * 4);
  float* wpre  = (float*)alloc((size_t)LL * BB * NHH * 4);
  float* wsoft = (float*)alloc((size_t)LL * BB * NHH * 4);
  float* ctxb  = (float*)alloc((size_t)BB * NHH * HH * 4);
  half_t* Wa0Ta = (half_t*)alloc((size_t)128 * 128 * 2);
  half_t* Wa0Tb = (half_t*)alloc((size_t)128 * 128 * 2);
  half2v* Wih0T2 = (half2v*)alloc((size_t)65 * 768 * 4);
  half2v* Wih1T2 = (half2v*)alloc((size_t)128 * 768 * 4);
  half_t* Whh0h = (half_t*)alloc((size_t)G3 * HH * 2);
  half_t* Whh1h = (half_t*)alloc((size_t)G3 * HH * 2);
  if (off > ws_size) return;  // workspace too small: fail visibly

  const int prep_total = 16384 + 16384 + 65 * 768 + 128 * 768 + 196608 + 196608;
  prep_kernel<<<(prep_total + 255) / 256, 256, 0, stream>>>(
      Wa0, Wih0, Wih1, Whh0, Whh1, Wa0Ta, Wa0Tb, Wih0T2, Wih1T2, Whh0h, Whh1h);
  embed_uv_kernel<<<LL * BB, 128, 0, stream>>>(node, table, Wa0Ta, Wa0Tb, ba0, e_h2, U, V);
  attn_w_kernel<<<(LL / 4) * BB, 128, 0, stream>>>(U, V, Wa1, ba1, wpre);
  attn_softmax_kernel<<<BB * NHH, 128, 0, stream>>>(wpre, slen, wsoft);
  gi0_kernel<<<LL * BB / 8, 256, 0, stream>>>(e_h2, ts, Wih0T2, bih0, gi);
  gru_scan_kernel<<<BB, 256, 0, stream>>>(Whh0h, bhh0, gi, slen, out0, hTb);
  gi1_kernel<<<LL * BB / 8, 256, 0, stream>>>(out0, Wih1T2, bih1, gi);
  gru_scan_kernel<<<BB, 256, 0, stream>>>(Whh1h, bhh1, gi, slen, out1, hTb);
  ctx_kernel<<<BB * NHH, 256, 0, stream>>>(wsoft, out1, ctxb);
  final_kernel<<<BB, 512, 0, stream>>>(ctxb, hTb, Wf0, bf0, Wf1, bf1, (float*)d_out);
}

// Round 7
// 778.131 us; speedup vs baseline: 1.0120x; 1.0120x over previous
//
#include <hip/hip_runtime.h>
#include <hip/hip_bf16.h>

#define LL 128
#define BB 32
#define EE 128
#define HH 256
#define NHH 8
#define G3 768   // 3*H
#define IN0 130
#define ETA 100
#define F1 168
#define CLSIN 2304  // 8*256 + 256

typedef _Float16 half_t;
typedef __attribute__((ext_vector_type(2))) _Float16 half2v;
typedef __attribute__((ext_vector_type(8))) _Float16 half8v;
typedef __attribute__((ext_vector_type(4))) float floatx4;

#if defined(__has_builtin)
#if __has_builtin(__builtin_amdgcn_fdot2)
#define HAVE_FDOT2 1
#endif
#endif

__device__ __forceinline__ float fdot2f(half2v a, half2v b, float c) {
#ifdef HAVE_FDOT2
  return __builtin_amdgcn_fdot2(a, b, c, false);
#else
  return c + (float)a.x * (float)b.x + (float)a.y * (float)b.y;
#endif
}

// LDS-only barrier: skip the compiler's vmcnt(0) drain (no cross-thread
// global-memory dependencies at our barriers).
#define BARRIER_LDS() __asm__ volatile("s_waitcnt lgkmcnt(0)\n\ts_barrier" ::: "memory")

__device__ __forceinline__ float sigmoidf_(float x) { return 1.0f / (1.0f + __expf(-x)); }
__device__ __forceinline__ float tanhf_(float x) { return 1.0f - 2.0f / (__expf(2.0f * x) + 1.0f); }

// ---------------------------------------------------------------------------
// prep: weight repack fp32 -> f16 (weights ~N(0,0.05^2): f16 rel err 5e-4)
// ---------------------------------------------------------------------------
__global__ void prep_kernel(
    const float* __restrict__ Wa0, const float* __restrict__ Wih0,
    const float* __restrict__ Wih1, const float* __restrict__ Whh0,
    const float* __restrict__ Whh1,
    half_t* __restrict__ Wa0Ta, half_t* __restrict__ Wa0Tb,
    half2v* __restrict__ Wih0T2, half2v* __restrict__ Wih1T2,
    half_t* __restrict__ Whh0h, half_t* __restrict__ Whh1h)
{
  int idx = blockIdx.x * blockDim.x + threadIdx.x;
  const int n1 = 16384, n2 = 16384, n3 = 65 * 768, n4 = 128 * 768, n5 = 196608;
  if (idx < n1) {
    int d = idx >> 7, k = idx & 127;
    Wa0Ta[idx] = (half_t)Wa0[k * 256 + d];
  } else if ((idx -= n1) < n2) {
    int d = idx >> 7, k = idx & 127;
    Wa0Tb[idx] = (half_t)Wa0[k * 256 + 128 + d];
  } else if ((idx -= n2) < n3) {
    int d2 = idx / 768, r = idx % 768;
    half2v w; w.x = (half_t)Wih0[r * IN0 + 2 * d2]; w.y = (half_t)Wih0[r * IN0 + 2 * d2 + 1];
    Wih0T2[idx] = w;
  } else if ((idx -= n3) < n4) {
    int d2 = idx / 768, r = idx % 768;
    half2v w; w.x = (half_t)Wih1[r * HH + 2 * d2]; w.y = (half_t)Wih1[r * HH + 2 * d2 + 1];
    Wih1T2[idx] = w;
  } else if ((idx -= n4) < n5) {
    Whh0h[idx] = (half_t)Whh0[idx];
  } else if ((idx -= n5) < n5) {
    Whh1h[idx] = (half_t)Whh1[idx];
  }
}

// ---------------------------------------------------------------------------
// embed gather + U/V factors of the pairwise attention
// ---------------------------------------------------------------------------
__global__ void embed_uv_kernel(
    const int* __restrict__ node,             // [L*B]
    const float* __restrict__ table,          // [20001][128]
    const half_t* __restrict__ Wa0Ta,         // [128 d][128 k]
    const half_t* __restrict__ Wa0Tb,
    const float* __restrict__ ba0,            // [128]
    half2v* __restrict__ e_h2,                // [L*B][64]
    float* __restrict__ U,
    float* __restrict__ V)
{
  int lb = blockIdx.x;
  int k = threadIdx.x;  // 128
  __shared__ float es[EE];
  int n = node[lb];
  float ev = table[(size_t)n * EE + k];
  es[k] = ev;
  __syncthreads();
  if (k < 64) {
    half2v p; p.x = (half_t)es[2 * k]; p.y = (half_t)es[2 * k + 1];
    e_h2[(size_t)lb * 64 + k] = p;
  }
  float u = 0.f, v = ba0[k];
  #pragma unroll 8
  for (int d = 0; d < EE; ++d) {
    float x = es[d];
    u += (float)Wa0Ta[d * EE + k] * x;
    v += (float)Wa0Tb[d * EE + k] * x;
  }
  U[(size_t)lb * EE + k] = u;
  V[(size_t)lb * EE + k] = v;
}

// ---------------------------------------------------------------------------
// w_pre[i,b,h] = sum_j sum_k Wa1[h,k] * relu(U[j,b,k]+V[i,b,k]) + L*ba1[h]
// ---------------------------------------------------------------------------
__global__ __launch_bounds__(128) void attn_w_kernel(
    const float* __restrict__ U, const float* __restrict__ V,
    const float* __restrict__ Wa1,  // [8][128]
    const float* __restrict__ ba1,  // [8]
    float* __restrict__ wpre)       // [L][B][8]
{
  int ig = blockIdx.x >> 5;
  int b = blockIdx.x & 31;
  int i0 = ig * 4;
  int k = threadIdx.x;  // 128
  float vk[4];
  #pragma unroll
  for (int ii = 0; ii < 4; ++ii) vk[ii] = V[((size_t)(i0 + ii) * BB + b) * EE + k];
  float wa[NHH], acc[4][NHH];
  #pragma unroll
  for (int h = 0; h < NHH; ++h) wa[h] = Wa1[h * EE + k];
  #pragma unroll
  for (int ii = 0; ii < 4; ++ii)
    #pragma unroll
    for (int h = 0; h < NHH; ++h) acc[ii][h] = 0.f;
  for (int j = 0; j < LL; ++j) {
    float u = U[((size_t)j * BB + b) * EE + k];
    #pragma unroll
    for (int ii = 0; ii < 4; ++ii) {
      float tv = fmaxf(u + vk[ii], 0.f);
      #pragma unroll
      for (int h = 0; h < NHH; ++h) acc[ii][h] += wa[h] * tv;
    }
  }
  __shared__ float part[2][32];
  int wave = k >> 6, lane = k & 63;
  #pragma unroll
  for (int ii = 0; ii < 4; ++ii)
    #pragma unroll
    for (int h = 0; h < NHH; ++h) {
      float a = acc[ii][h];
      #pragma unroll
      for (int off = 32; off > 0; off >>= 1) a += __shfl_xor(a, off, 64);
      if (lane == 0) part[wave][ii * 8 + h] = a;
    }
  __syncthreads();
  if (k < 32) {
    int ii = k >> 3, h = k & 7;
    float w = part[0][k] + part[1][k] + (float)LL * ba1[h];
    wpre[((size_t)(i0 + ii) * BB + b) * NHH + h] = w;
  }
}

// softmax over l of (w * mask): masked entries become 0 and STAY in the softmax
__global__ void attn_softmax_kernel(
    const float* __restrict__ wpre, const int* __restrict__ slen,
    float* __restrict__ wsoft)
{
  int b = blockIdx.x >> 3;
  int h = blockIdx.x & 7;
  int l = threadIdx.x;  // 128
  int len = slen[b];
  float x = wpre[((size_t)l * BB + b) * NHH + h];
  float xv = (l < len) ? x : 0.f;
  float m = xv;
  #pragma unroll
  for (int off = 32; off > 0; off >>= 1) m = fmaxf(m, __shfl_xor(m, off, 64));
  __shared__ float sm[2], ss[2];
  int wave = l >> 6;
  if ((l & 63) == 0) sm[wave] = m;
  __syncthreads();
  m = fmaxf(sm[0], sm[1]);
  float e = __expf(xv - m);
  float s = e;
  #pragma unroll
  for (int off = 32; off > 0; off >>= 1) s += __shfl_xor(s, off, 64);
  if ((l & 63) == 0) ss[wave] = s;
  __syncthreads();
  s = ss[0] + ss[1];
  wsoft[((size_t)l * BB + b) * NHH + h] = e / s;
}

// ---------------------------------------------------------------------------
// gi0: [e, ts] @ Wih0.T + bih0, 8 lb per block, v_dot2 on packed pairs
// ---------------------------------------------------------------------------
__global__ __launch_bounds__(256) void gi0_kernel(
    const half2v* __restrict__ e_h2, const float* __restrict__ ts,
    const half2v* __restrict__ W2,   // [65][768]
    const float* __restrict__ bih,
    float* __restrict__ gi)
{
  int lb0 = blockIdx.x * 8;
  int tid = threadIdx.x;  // 256
  __shared__ half2v xs2[8][66];
  for (int idx = tid; idx < 512; idx += 256) {
    int q = idx >> 6, d2 = idx & 63;
    xs2[q][d2] = e_h2[(size_t)(lb0 + q) * 64 + d2];
  }
  if (tid < 8) {
    half2v t2; t2.x = (half_t)ts[(lb0 + tid) * 2]; t2.y = (half_t)ts[(lb0 + tid) * 2 + 1];
    xs2[tid][64] = t2;
  }
  __syncthreads();
  float acc[8][3];
  #pragma unroll
  for (int q = 0; q < 8; ++q) { acc[q][0] = 0.f; acc[q][1] = 0.f; acc[q][2] = 0.f; }
  for (int d2 = 0; d2 < 65; ++d2) {
    half2v w0 = W2[d2 * 768 + tid];
    half2v w1 = W2[d2 * 768 + 256 + tid];
    half2v w2 = W2[d2 * 768 + 512 + tid];
    #pragma unroll
    for (int q = 0; q < 8; ++q) {
      half2v x = xs2[q][d2];
      acc[q][0] = fdot2f(w0, x, acc[q][0]);
      acc[q][1] = fdot2f(w1, x, acc[q][1]);
      acc[q][2] = fdot2f(w2, x, acc[q][2]);
    }
  }
  float b0 = bih[tid], b1 = bih[256 + tid], b2 = bih[512 + tid];
  #pragma unroll
  for (int q = 0; q < 8; ++q) {
    float* gp = gi + (size_t)(lb0 + q) * G3;
    gp[tid] = acc[q][0] + b0; gp[256 + tid] = acc[q][1] + b1; gp[512 + tid] = acc[q][2] + b2;
  }
}

// ---------------------------------------------------------------------------
// gi1: out0 @ Wih1.T + bih1, 8 lb per block
// ---------------------------------------------------------------------------
__global__ __launch_bounds__(256) void gi1_kernel(
    const float* __restrict__ out0,  // [L*B][256]
    const half2v* __restrict__ W2,   // [128][768]
    const float* __restrict__ bih,
    float* __restrict__ gi)
{
  int lb0 = blockIdx.x * 8;
  int tid = threadIdx.x;  // 256
  __shared__ half2v xs2[8][128];
  for (int idx = tid; idx < 1024; idx += 256) {
    int q = idx >> 7, d2 = idx & 127;
    float2 v = ((const float2*)(out0 + (size_t)(lb0 + q) * HH))[d2];
    half2v x; x.x = (half_t)v.x; x.y = (half_t)v.y;
    xs2[q][d2] = x;
  }
  __syncthreads();
  float acc[8][3];
  #pragma unroll
  for (int q = 0; q < 8; ++q) { acc[q][0] = 0.f; acc[q][1] = 0.f; acc[q][2] = 0.f; }
  for (int d2 = 0; d2 < 128; ++d2) {
    half2v w0 = W2[d2 * 768 + tid];
    half2v w1 = W2[d2 * 768 + 256 + tid];
    half2v w2 = W2[d2 * 768 + 512 + tid];
    #pragma unroll
    for (int q = 0; q < 8; ++q) {
      half2v x = xs2[q][d2];
      acc[q][0] = fdot2f(w0, x, acc[q][0]);
      acc[q][1] = fdot2f(w1, x, acc[q][1]);
      acc[q][2] = fdot2f(w2, x, acc[q][2]);
    }
  }
  float b0 = bih[tid], b1 = bih[256 + tid], b2 = bih[512 + tid];
  #pragma unroll
  for (int q = 0; q < 8; ++q) {
    float* gp = gi + (size_t)(lb0 + q) * G3;
    gp[tid] = acc[q][0] + b0; gp[256 + tid] = acc[q][1] + b1; gp[512 + tid] = acc[q][2] + b2;
  }
}

// ---------------------------------------------------------------------------
// GRU scan, MFMA edition. One block per batch, 256 threads = 4 waves =
// 1 wave/SIMD => unified VGPR+AGPR budget 512 regs/thread. Wave w owns
// h-indices [64w,64w+64) for all 3 gates = 12 16x16 tiles x 8 k-steps of
// mfma_f32_16x16x32_f16. The 96 weight fragments (384 regs) stay resident
// across the t-loop (MFMA reads A/B from VGPR or AGPR — this is the only
// way to use the AGPR half of the file; v_dot2 cannot).
// A-operand = h replicated over M (A[m][k]=h[k]: quad q loads h[32ks+8q..+8]
// from LDS, broadcast within quad). B[n=lane&15][k=quad*8+j] = row-major W
// rows. D: out[n=lane&15] in every reg (rows identical). gi prefetched one
// step ahead in registers.
// ---------------------------------------------------------------------------
__global__ __launch_bounds__(256, 1) void gru_scan_kernel(
    const half_t* __restrict__ Whhh,         // [768][256] f16
    const float* __restrict__ bhh,           // [768]
    const float* __restrict__ gi,            // [L][B][768]
    const int* __restrict__ slen,            // [B]
    float* __restrict__ out,                 // [L][B][256]
    float* __restrict__ hT)                  // [B][256]
{
  const int b = blockIdx.x;
  const int tid = threadIdx.x;  // 256
  const int w = tid >> 6;
  const int lane = tid & 63;
  const int col = lane & 15;
  const int quad = lane >> 4;
  __shared__ __align__(16) half_t hs[HH];

  // 96 resident weight fragments: wf[(g3*4+tau)*8 + ks]
  half8v wf[96];
  #pragma unroll
  for (int g3 = 0; g3 < 3; ++g3) {
    #pragma unroll
    for (int tau = 0; tau < 4; ++tau) {
      int row = 256 * g3 + 64 * w + 16 * tau + col;
      const half8v* rp = (const half8v*)(Whhh + (size_t)row * HH + 8 * quad);
      #pragma unroll
      for (int ks = 0; ks < 8; ++ks)
        wf[(g3 * 4 + tau) * 8 + ks] = rp[ks * 4];  // +32 halfs per ks
    }
  }

  const int len = slen[b];
  float hold[4], br[4], bz[4], bn[4];
  #pragma unroll
  for (int tau = 0; tau < 4; ++tau) {
    int j = 64 * w + 16 * tau + col;
    hold[tau] = 0.f;
    br[tau] = bhh[j]; bz[tau] = bhh[256 + j]; bn[tau] = bhh[512 + j];
  }
  if (tid < 128) { half2v z0; z0.x = (half_t)0.f; z0.y = (half_t)0.f; ((half2v*)hs)[tid] = z0; }
  __syncthreads();

  const float* gib = gi + (size_t)b * G3;
  float* outb = out + (size_t)b * HH;

  // gi for t=0
  float c0[4], c1[4], c2[4];
  #pragma unroll
  for (int tau = 0; tau < 4; ++tau) {
    int j = 64 * w + 16 * tau + col;
    c0[tau] = gib[j]; c1[tau] = gib[256 + j]; c2[tau] = gib[512 + j];
  }

  #pragma unroll 1
  for (int t = 0; t < LL; ++t) {
    // prefetch gi for t+1 (full step of latency cover)
    int t2 = (t + 1 < LL) ? (t + 1) : t;
    const float* gq = gib + (size_t)t2 * (BB * G3);
    float n0[4], n1[4], n2[4];
    #pragma unroll
    for (int tau = 0; tau < 4; ++tau) {
      int j = 64 * w + 16 * tau + col;
      n0[tau] = gq[j]; n1[tau] = gq[256 + j]; n2[tau] = gq[512 + j];
    }
    floatx4 acc[12];
    #pragma unroll
    for (int i = 0; i < 12; ++i) { floatx4 z = {0.f, 0.f, 0.f, 0.f}; acc[i] = z; }
    #pragma unroll
    for (int ks = 0; ks < 8; ++ks) {
      half8v hfrag = *(const half8v*)(hs + 32 * ks + 8 * quad);
      #pragma unroll
      for (int tt = 0; tt < 12; ++tt)
        acc[tt] = __builtin_amdgcn_mfma_f32_16x16x32_f16(hfrag, wf[tt * 8 + ks], acc[tt], 0, 0, 0);
    }
    BARRIER_LDS();  // all waves done reading hs
    bool valid = t < len;
    #pragma unroll
    for (int tau = 0; tau < 4; ++tau) {
      float r_ = sigmoidf_(c0[tau] + acc[tau].x + br[tau]);
      float z_ = sigmoidf_(c1[tau] + acc[4 + tau].x + bz[tau]);
      float nn = tanhf_(c2[tau] + r_ * (acc[8 + tau].x + bn[tau]));
      float hnew = (1.f - z_) * nn + z_ * hold[tau];
      hold[tau] = valid ? hnew : hold[tau];
      if (lane < 16) {
        int j = 64 * w + 16 * tau + col;
        hs[j] = (half_t)hold[tau];
        outb[(size_t)t * (BB * HH) + j] = valid ? hnew : 0.f;
      }
      c0[tau] = n0[tau]; c1[tau] = n1[tau]; c2[tau] = n2[tau];
    }
    BARRIER_LDS();
  }
  if (lane < 16) {
    #pragma unroll
    for (int tau = 0; tau < 4; ++tau)
      hT[(size_t)b * HH + 64 * w + 16 * tau + col] = hold[tau];
  }
}

// ---------------------------------------------------------------------------
// ctx[b, h*256+d] = sum_l wsoft[l,b,h] * out1[l,b,d]
// ---------------------------------------------------------------------------
__global__ void ctx_kernel(
    const float* __restrict__ wsoft, const float* __restrict__ out1,
    float* __restrict__ ctx)
{
  int b = blockIdx.x >> 3, h = blockIdx.x & 7;
  int d = threadIdx.x;  // 256
  float acc = 0.f;
  for (int l = 0; l < LL; ++l) {
    float w = wsoft[((size_t)l * BB + b) * NHH + h];
    acc += w * out1[((size_t)l * BB + b) * HH + d];
  }
  ctx[(size_t)b * (NHH * HH) + h * HH + d] = acc;
}

// ---------------------------------------------------------------------------
// final MLP: z = selu([ctx, hT] @ Wf0.T + bf0); logits = z @ Wf1.T + bf1;
// out = log_softmax(logits)
// ---------------------------------------------------------------------------
__global__ __launch_bounds__(512) void final_kernel(
    const float* __restrict__ ctx, const float* __restrict__ hT,
    const float* __restrict__ Wf0,   // [168][2304]
    const float* __restrict__ bf0,
    const float* __restrict__ Wf1,   // [100][168]
    const float* __restrict__ bf1,
    float* __restrict__ outp)        // [B][100]
{
  int b = blockIdx.x;
  int tid = threadIdx.x;
  int wave = tid >> 6, lane = tid & 63;
  __shared__ float4 xs4[CLSIN / 4];
  __shared__ float zs[F1];
  __shared__ float ls[ETA];
  float* xs = (float*)xs4;
  for (int i = tid; i < NHH * HH; i += 512) xs[i] = ctx[(size_t)b * (NHH * HH) + i];
  if (tid < HH) xs[NHH * HH + tid] = hT[(size_t)b * HH + tid];
  __syncthreads();
  for (int r = wave; r < F1; r += 8) {
    const float4* wp = (const float4*)(Wf0 + (size_t)r * CLSIN);
    float acc = 0.f;
    #pragma unroll
    for (int i = 0; i < CLSIN / 4 / 64; ++i) {  // 9
      float4 w = wp[lane + 64 * i];
      float4 x = xs4[lane + 64 * i];
      acc += w.x * x.x + w.y * x.y + w.z * x.z + w.w * x.w;
    }
    #pragma unroll
    for (int off = 32; off > 0; off >>= 1) acc += __shfl_xor(acc, off, 64);
    if (lane == 0) {
      float x = acc + bf0[r];
      const float alpha = 1.6732632423543772f, scale = 1.0507009873554805f;
      zs[r] = scale * (x > 0.f ? x : alpha * (__expf(x) - 1.f));
    }
  }
  __syncthreads();
  for (int r = wave; r < ETA; r += 8) {
    float acc = 0.f;
    for (int k = lane; k < F1; k += 64) acc += Wf1[r * F1 + k] * zs[k];
    #pragma unroll
    for (int off = 32; off > 0; off >>= 1) acc += __shfl_xor(acc, off, 64);
    if (lane == 0) ls[r] = acc + bf1[r];
  }
  __syncthreads();
  if (wave == 0) {
    float v0 = (lane < ETA) ? ls[lane] : -1e30f;
    float v1 = (lane + 64 < ETA) ? ls[lane + 64] : -1e30f;
    float m = fmaxf(v0, v1);
    #pragma unroll
    for (int off = 32; off > 0; off >>= 1) m = fmaxf(m, __shfl_xor(m, off, 64));
    float s = __expf(v0 - m) + __expf(v1 - m);
    #pragma unroll
    for (int off = 32; off > 0; off >>= 1) s += __shfl_xor(s, off, 64);
    float lse = m + __logf(s);
    if (lane < ETA) outp[(size_t)b * ETA + lane] = v0 - lse;
    if (lane + 64 < ETA) outp[(size_t)b * ETA + lane + 64] = v1 - lse;
  }
}

extern "C" void kernel_launch(void* const* d_in, const int* in_sizes, int n_in,
                              void* d_out, int out_size, void* d_ws, size_t ws_size,
                              hipStream_t stream) {
  const int*   node  = (const int*)d_in[0];
  const float* ts    = (const float*)d_in[1];
  const int*   slen  = (const int*)d_in[2];
  const float* table = (const float*)d_in[3];
  const float* Wih0  = (const float*)d_in[4];
  const float* Whh0  = (const float*)d_in[5];
  const float* bih0  = (const float*)d_in[6];
  const float* bhh0  = (const float*)d_in[7];
  const float* Wih1  = (const float*)d_in[8];
  const float* Whh1  = (const float*)d_in[9];
  const float* bih1  = (const float*)d_in[10];
  const float* bhh1  = (const float*)d_in[11];
  const float* Wa0   = (const float*)d_in[12];
  const float* ba0   = (const float*)d_in[13];
  const float* Wa1   = (const float*)d_in[14];
  const float* ba1   = (const float*)d_in[15];
  const float* Wf0   = (const float*)d_in[16];
  const float* bf0   = (const float*)d_in[17];
  const float* Wf1   = (const float*)d_in[18];
  const float* bf1   = (const float*)d_in[19];

  char* ws = (char*)d_ws;
  size_t off = 0;
  auto alloc = [&](size_t n) { void* p = (void*)(ws + off); off += (n + 255) & ~(size_t)255; return p; };

  half2v* e_h2 = (half2v*)alloc((size_t)LL * BB * 64 * 4);
  float* U     = (float*)alloc((size_t)LL * BB * EE * 4);
  float* V     = (float*)alloc((size_t)LL * BB * EE * 4);
  float* gi    = (float*)alloc((size_t)LL * BB * G3 * 4);   // reused for both layers
  float* out0  = (float*)alloc((size_t)LL * BB * HH * 4);
  float* out1  = (float*)alloc((size_t)LL * BB * HH * 4);
  float* hTb   = (float*)alloc((size_t)BB * HH * 4);
  float* wpre  = (float*)alloc((size_t)LL * BB * NHH * 4);
  float* wsoft = (float*)alloc((size_t)LL * BB * NHH * 4);
  float* ctxb  = (float*)alloc((size_t)BB * NHH * HH * 4);
  half_t* Wa0Ta = (half_t*)alloc((size_t)128 * 128 * 2);
  half_t* Wa0Tb = (half_t*)alloc((size_t)128 * 128 * 2);
  half2v* Wih0T2 = (half2v*)alloc((size_t)65 * 768 * 4);
  half2v* Wih1T2 = (half2v*)alloc((size_t)128 * 768 * 4);
  half_t* Whh0h = (half_t*)alloc((size_t)G3 * HH * 2);
  half_t* Whh1h = (half_t*)alloc((size_t)G3 * HH * 2);
  if (off > ws_size) return;  // workspace too small: fail visibly

  const int prep_total = 16384 + 16384 + 65 * 768 + 128 * 768 + 196608 + 196608;
  prep_kernel<<<(prep_total + 255) / 256, 256, 0, stream>>>(
      Wa0, Wih0, Wih1, Whh0, Whh1, Wa0Ta, Wa0Tb, Wih0T2, Wih1T2, Whh0h, Whh1h);
  embed_uv_kernel<<<LL * BB, 128, 0, stream>>>(node, table, Wa0Ta, Wa0Tb, ba0, e_h2, U, V);
  attn_w_kernel<<<(LL / 4) * BB, 128, 0, stream>>>(U, V, Wa1, ba1, wpre);
  attn_softmax_kernel<<<BB * NHH, 128, 0, stream>>>(wpre, slen, wsoft);
  gi0_kernel<<<LL * BB / 8, 256, 0, stream>>>(e_h2, ts, Wih0T2, bih0, gi);
  gru_scan_kernel<<<BB, 256, 0, stream>>>(Whh0h, bhh0, gi, slen, out0, hTb);
  gi1_kernel<<<LL * BB / 8, 256, 0, stream>>>(out0, Wih1T2, bih1, gi);
  gru_scan_kernel<<<BB, 256, 0, stream>>>(Whh1h, bhh1, gi, slen, out1, hTb);
  ctx_kernel<<<BB * NHH, 256, 0, stream>>>(wsoft, out1, ctxb);
  final_kernel<<<BB, 512, 0, stream>>>(ctxb, hTb, Wf0, bf0, Wf1, bf1, (float*)d_out);
}

// Round 8
// 694.471 us; speedup vs baseline: 1.1339x; 1.1205x over previous
//
#include <hip/hip_runtime.h>
#include <hip/hip_bf16.h>
#include <hip/hip_fp8.h>

#define LL 128
#define BB 32
#define EE 128
#define HH 256
#define NHH 8
#define G3 768   // 3*H
#define IN0 130
#define ETA 100
#define F1 168
#define CLSIN 2304  // 8*256 + 256

typedef _Float16 half_t;
typedef __attribute__((ext_vector_type(2))) _Float16 half2v;
typedef __attribute__((ext_vector_type(4))) float floatx4;

#if defined(__has_builtin)
#if __has_builtin(__builtin_amdgcn_fdot2)
#define HAVE_FDOT2 1
#endif
#endif

__device__ __forceinline__ float fdot2f(half2v a, half2v b, float c) {
#ifdef HAVE_FDOT2
  return __builtin_amdgcn_fdot2(a, b, c, false);
#else
  return c + (float)a.x * (float)b.x + (float)a.y * (float)b.y;
#endif
}

// LDS-only barrier: skip the compiler's vmcnt(0) drain (no cross-thread
// global-memory dependencies at our barriers).
#define BARRIER_LDS() __asm__ volatile("s_waitcnt lgkmcnt(0)\n\ts_barrier" ::: "memory")

__device__ __forceinline__ float sigmoidf_(float x) { return 1.0f / (1.0f + __expf(-x)); }
__device__ __forceinline__ float tanhf_(float x) { return 1.0f - 2.0f / (__expf(2.0f * x) + 1.0f); }

// ---------------------------------------------------------------------------
// prep: weight repack. Wa0/Wih -> f16 (rel err 5e-4). Whh -> fp8 e4m3 (OCP):
// sigma=0.05, |w|max~0.25 well inside e4m3 range; |w|<2^-9 (3% of mass)
// quantizes to ~0 with negligible contribution.
// ---------------------------------------------------------------------------
__global__ void prep_kernel(
    const float* __restrict__ Wa0, const float* __restrict__ Wih0,
    const float* __restrict__ Wih1, const float* __restrict__ Whh0,
    const float* __restrict__ Whh1,
    half_t* __restrict__ Wa0Ta, half_t* __restrict__ Wa0Tb,
    half2v* __restrict__ Wih0T2, half2v* __restrict__ Wih1T2,
    __hip_fp8_e4m3* __restrict__ Whh0q, __hip_fp8_e4m3* __restrict__ Whh1q)
{
  int idx = blockIdx.x * blockDim.x + threadIdx.x;
  const int n1 = 16384, n2 = 16384, n3 = 65 * 768, n4 = 128 * 768, n5 = 196608;
  if (idx < n1) {
    int d = idx >> 7, k = idx & 127;
    Wa0Ta[idx] = (half_t)Wa0[k * 256 + d];
  } else if ((idx -= n1) < n2) {
    int d = idx >> 7, k = idx & 127;
    Wa0Tb[idx] = (half_t)Wa0[k * 256 + 128 + d];
  } else if ((idx -= n2) < n3) {
    int d2 = idx / 768, r = idx % 768;
    half2v w; w.x = (half_t)Wih0[r * IN0 + 2 * d2]; w.y = (half_t)Wih0[r * IN0 + 2 * d2 + 1];
    Wih0T2[idx] = w;
  } else if ((idx -= n3) < n4) {
    int d2 = idx / 768, r = idx % 768;
    half2v w; w.x = (half_t)Wih1[r * HH + 2 * d2]; w.y = (half_t)Wih1[r * HH + 2 * d2 + 1];
    Wih1T2[idx] = w;
  } else if ((idx -= n4) < n5) {
    Whh0q[idx] = __hip_fp8_e4m3(Whh0[idx]);
  } else if ((idx -= n5) < n5) {
    Whh1q[idx] = __hip_fp8_e4m3(Whh1[idx]);
  }
}

// ---------------------------------------------------------------------------
// embed gather + U/V factors of the pairwise attention
// ---------------------------------------------------------------------------
__global__ void embed_uv_kernel(
    const int* __restrict__ node,             // [L*B]
    const float* __restrict__ table,          // [20001][128]
    const half_t* __restrict__ Wa0Ta,         // [128 d][128 k]
    const half_t* __restrict__ Wa0Tb,
    const float* __restrict__ ba0,            // [128]
    half2v* __restrict__ e_h2,                // [L*B][64]
    float* __restrict__ U,
    float* __restrict__ V)
{
  int lb = blockIdx.x;
  int k = threadIdx.x;  // 128
  __shared__ float es[EE];
  int n = node[lb];
  float ev = table[(size_t)n * EE + k];
  es[k] = ev;
  __syncthreads();
  if (k < 64) {
    half2v p; p.x = (half_t)es[2 * k]; p.y = (half_t)es[2 * k + 1];
    e_h2[(size_t)lb * 64 + k] = p;
  }
  float u = 0.f, v = ba0[k];
  #pragma unroll 8
  for (int d = 0; d < EE; ++d) {
    float x = es[d];
    u += (float)Wa0Ta[d * EE + k] * x;
    v += (float)Wa0Tb[d * EE + k] * x;
  }
  U[(size_t)lb * EE + k] = u;
  V[(size_t)lb * EE + k] = v;
}

// ---------------------------------------------------------------------------
// w_pre[i,b,h] = sum_j sum_k Wa1[h,k] * relu(U[j,b,k]+V[i,b,k]) + L*ba1[h]
// ---------------------------------------------------------------------------
__global__ __launch_bounds__(128) void attn_w_kernel(
    const float* __restrict__ U, const float* __restrict__ V,
    const float* __restrict__ Wa1,  // [8][128]
    const float* __restrict__ ba1,  // [8]
    float* __restrict__ wpre)       // [L][B][8]
{
  int ig = blockIdx.x >> 5;
  int b = blockIdx.x & 31;
  int i0 = ig * 4;
  int k = threadIdx.x;  // 128
  float vk[4];
  #pragma unroll
  for (int ii = 0; ii < 4; ++ii) vk[ii] = V[((size_t)(i0 + ii) * BB + b) * EE + k];
  float wa[NHH], acc[4][NHH];
  #pragma unroll
  for (int h = 0; h < NHH; ++h) wa[h] = Wa1[h * EE + k];
  #pragma unroll
  for (int ii = 0; ii < 4; ++ii)
    #pragma unroll
    for (int h = 0; h < NHH; ++h) acc[ii][h] = 0.f;
  for (int j = 0; j < LL; ++j) {
    float u = U[((size_t)j * BB + b) * EE + k];
    #pragma unroll
    for (int ii = 0; ii < 4; ++ii) {
      float tv = fmaxf(u + vk[ii], 0.f);
      #pragma unroll
      for (int h = 0; h < NHH; ++h) acc[ii][h] += wa[h] * tv;
    }
  }
  __shared__ float part[2][32];
  int wave = k >> 6, lane = k & 63;
  #pragma unroll
  for (int ii = 0; ii < 4; ++ii)
    #pragma unroll
    for (int h = 0; h < NHH; ++h) {
      float a = acc[ii][h];
      #pragma unroll
      for (int off = 32; off > 0; off >>= 1) a += __shfl_xor(a, off, 64);
      if (lane == 0) part[wave][ii * 8 + h] = a;
    }
  __syncthreads();
  if (k < 32) {
    int ii = k >> 3, h = k & 7;
    float w = part[0][k] + part[1][k] + (float)LL * ba1[h];
    wpre[((size_t)(i0 + ii) * BB + b) * NHH + h] = w;
  }
}

// softmax over l of (w * mask): masked entries become 0 and STAY in the softmax
__global__ void attn_softmax_kernel(
    const float* __restrict__ wpre, const int* __restrict__ slen,
    float* __restrict__ wsoft)
{
  int b = blockIdx.x >> 3;
  int h = blockIdx.x & 7;
  int l = threadIdx.x;  // 128
  int len = slen[b];
  float x = wpre[((size_t)l * BB + b) * NHH + h];
  float xv = (l < len) ? x : 0.f;
  float m = xv;
  #pragma unroll
  for (int off = 32; off > 0; off >>= 1) m = fmaxf(m, __shfl_xor(m, off, 64));
  __shared__ float sm[2], ss[2];
  int wave = l >> 6;
  if ((l & 63) == 0) sm[wave] = m;
  __syncthreads();
  m = fmaxf(sm[0], sm[1]);
  float e = __expf(xv - m);
  float s = e;
  #pragma unroll
  for (int off = 32; off > 0; off >>= 1) s += __shfl_xor(s, off, 64);
  if ((l & 63) == 0) ss[wave] = s;
  __syncthreads();
  s = ss[0] + ss[1];
  wsoft[((size_t)l * BB + b) * NHH + h] = e / s;
}

// ---------------------------------------------------------------------------
// gi0: [e, ts] @ Wih0.T + bih0, 8 lb per block, v_dot2 on packed pairs
// ---------------------------------------------------------------------------
__global__ __launch_bounds__(256) void gi0_kernel(
    const half2v* __restrict__ e_h2, const float* __restrict__ ts,
    const half2v* __restrict__ W2,   // [65][768]
    const float* __restrict__ bih,
    float* __restrict__ gi)
{
  int lb0 = blockIdx.x * 8;
  int tid = threadIdx.x;  // 256
  __shared__ half2v xs2[8][66];
  for (int idx = tid; idx < 512; idx += 256) {
    int q = idx >> 6, d2 = idx & 63;
    xs2[q][d2] = e_h2[(size_t)(lb0 + q) * 64 + d2];
  }
  if (tid < 8) {
    half2v t2; t2.x = (half_t)ts[(lb0 + tid) * 2]; t2.y = (half_t)ts[(lb0 + tid) * 2 + 1];
    xs2[tid][64] = t2;
  }
  __syncthreads();
  float acc[8][3];
  #pragma unroll
  for (int q = 0; q < 8; ++q) { acc[q][0] = 0.f; acc[q][1] = 0.f; acc[q][2] = 0.f; }
  for (int d2 = 0; d2 < 65; ++d2) {
    half2v w0 = W2[d2 * 768 + tid];
    half2v w1 = W2[d2 * 768 + 256 + tid];
    half2v w2 = W2[d2 * 768 + 512 + tid];
    #pragma unroll
    for (int q = 0; q < 8; ++q) {
      half2v x = xs2[q][d2];
      acc[q][0] = fdot2f(w0, x, acc[q][0]);
      acc[q][1] = fdot2f(w1, x, acc[q][1]);
      acc[q][2] = fdot2f(w2, x, acc[q][2]);
    }
  }
  float b0 = bih[tid], b1 = bih[256 + tid], b2 = bih[512 + tid];
  #pragma unroll
  for (int q = 0; q < 8; ++q) {
    float* gp = gi + (size_t)(lb0 + q) * G3;
    gp[tid] = acc[q][0] + b0; gp[256 + tid] = acc[q][1] + b1; gp[512 + tid] = acc[q][2] + b2;
  }
}

// ---------------------------------------------------------------------------
// gi1: out0 @ Wih1.T + bih1, 8 lb per block
// ---------------------------------------------------------------------------
__global__ __launch_bounds__(256) void gi1_kernel(
    const float* __restrict__ out0,  // [L*B][256]
    const half2v* __restrict__ W2,   // [128][768]
    const float* __restrict__ bih,
    float* __restrict__ gi)
{
  int lb0 = blockIdx.x * 8;
  int tid = threadIdx.x;  // 256
  __shared__ half2v xs2[8][128];
  for (int idx = tid; idx < 1024; idx += 256) {
    int q = idx >> 7, d2 = idx & 127;
    float2 v = ((const float2*)(out0 + (size_t)(lb0 + q) * HH))[d2];
    half2v x; x.x = (half_t)v.x; x.y = (half_t)v.y;
    xs2[q][d2] = x;
  }
  __syncthreads();
  float acc[8][3];
  #pragma unroll
  for (int q = 0; q < 8; ++q) { acc[q][0] = 0.f; acc[q][1] = 0.f; acc[q][2] = 0.f; }
  for (int d2 = 0; d2 < 128; ++d2) {
    half2v w0 = W2[d2 * 768 + tid];
    half2v w1 = W2[d2 * 768 + 256 + tid];
    half2v w2 = W2[d2 * 768 + 512 + tid];
    #pragma unroll
    for (int q = 0; q < 8; ++q) {
      half2v x = xs2[q][d2];
      acc[q][0] = fdot2f(w0, x, acc[q][0]);
      acc[q][1] = fdot2f(w1, x, acc[q][1]);
      acc[q][2] = fdot2f(w2, x, acc[q][2]);
    }
  }
  float b0 = bih[tid], b1 = bih[256 + tid], b2 = bih[512 + tid];
  #pragma unroll
  for (int q = 0; q < 8; ++q) {
    float* gp = gi + (size_t)(lb0 + q) * G3;
    gp[tid] = acc[q][0] + b0; gp[256 + tid] = acc[q][1] + b1; gp[512 + tid] = acc[q][2] + b2;
  }
}

// ---------------------------------------------------------------------------
// GRU scan, fp8-MFMA edition. 256 threads = 4 waves = 1 wave/SIMD =>
// unified 512-reg budget. Wave w owns h-indices [64w,64w+64) x 3 gates
// = 12 16x16 tiles x 8 k-steps of mfma_f32_16x16x32_fp8_fp8. Weight
// fragments are fp8: 96 frags x 2 regs = 192 VGPRs (fits the 256 arch
// file WITH temps, unlike the 384-reg f16 ask of r7); accumulators can
// go to AGPRs. h is fp8 in LDS (256 B). Layout identical to the
// r7-verified f16 path (8 elems/lane, k=8*quad+j; D col=lane&15 —
// C/D layout is shape-determined, dtype-independent).
// ---------------------------------------------------------------------------
__global__ __launch_bounds__(256, 1) void gru_scan_kernel(
    const __hip_fp8_e4m3* __restrict__ Whhq, // [768][256] fp8
    const float* __restrict__ bhh,           // [768]
    const float* __restrict__ gi,            // [L][B][768]
    const int* __restrict__ slen,            // [B]
    float* __restrict__ out,                 // [L][B][256]
    float* __restrict__ hT)                  // [B][256]
{
  const int b = blockIdx.x;
  const int tid = threadIdx.x;  // 256
  const int w = tid >> 6;
  const int lane = tid & 63;
  const int col = lane & 15;
  const int quad = lane >> 4;
  __shared__ __align__(16) unsigned char hs[HH];  // h as fp8

  const unsigned char* Wq = (const unsigned char*)Whhq;

  // 96 resident fp8 weight fragments: wf[(g3*4+tau)*8 + ks], 2 regs each
  uint2 wf[96];
  #pragma unroll
  for (int g3 = 0; g3 < 3; ++g3) {
    #pragma unroll
    for (int tau = 0; tau < 4; ++tau) {
      int row = 256 * g3 + 64 * w + 16 * tau + col;
      const uint2* rp = (const uint2*)(Wq + (size_t)row * HH + 8 * quad);
      #pragma unroll
      for (int ks = 0; ks < 8; ++ks)
        wf[(g3 * 4 + tau) * 8 + ks] = rp[ks * 4];  // +32 bytes per ks
    }
  }

  const int len = slen[b];
  float hold[4], br[4], bz[4], bn[4];
  #pragma unroll
  for (int tau = 0; tau < 4; ++tau) {
    int j = 64 * w + 16 * tau + col;
    hold[tau] = 0.f;
    br[tau] = bhh[j]; bz[tau] = bhh[256 + j]; bn[tau] = bhh[512 + j];
  }
  if (tid < 64) ((unsigned int*)hs)[tid] = 0u;  // fp8 zero = 0x00
  __syncthreads();

  const float* gib = gi + (size_t)b * G3;
  float* outb = out + (size_t)b * HH;

  // gi for t=0
  float c0[4], c1[4], c2[4];
  #pragma unroll
  for (int tau = 0; tau < 4; ++tau) {
    int j = 64 * w + 16 * tau + col;
    c0[tau] = gib[j]; c1[tau] = gib[256 + j]; c2[tau] = gib[512 + j];
  }

  #pragma unroll 1
  for (int t = 0; t < LL; ++t) {
    // prefetch gi for t+1
    int t2 = (t + 1 < LL) ? (t + 1) : t;
    const float* gq = gib + (size_t)t2 * (BB * G3);
    float n0[4], n1[4], n2[4];
    #pragma unroll
    for (int tau = 0; tau < 4; ++tau) {
      int j = 64 * w + 16 * tau + col;
      n0[tau] = gq[j]; n1[tau] = gq[256 + j]; n2[tau] = gq[512 + j];
    }
    floatx4 acc[12];
    #pragma unroll
    for (int i = 0; i < 12; ++i) { floatx4 z = {0.f, 0.f, 0.f, 0.f}; acc[i] = z; }
    #pragma unroll
    for (int ks = 0; ks < 8; ++ks) {
      uint2 hf = *(const uint2*)(hs + 32 * ks + 8 * quad);
      long ha = __builtin_bit_cast(long, hf);
      #pragma unroll
      for (int tt = 0; tt < 12; ++tt)
        acc[tt] = __builtin_amdgcn_mfma_f32_16x16x32_fp8_fp8(
            ha, __builtin_bit_cast(long, wf[tt * 8 + ks]), acc[tt], 0, 0, 0);
    }
    BARRIER_LDS();  // all waves done reading hs
    bool valid = t < len;
    #pragma unroll
    for (int tau = 0; tau < 4; ++tau) {
      float r_ = sigmoidf_(c0[tau] + acc[tau].x + br[tau]);
      float z_ = sigmoidf_(c1[tau] + acc[4 + tau].x + bz[tau]);
      float nn = tanhf_(c2[tau] + r_ * (acc[8 + tau].x + bn[tau]));
      float hnew = (1.f - z_) * nn + z_ * hold[tau];
      hold[tau] = valid ? hnew : hold[tau];
      if (lane < 16) {
        int j = 64 * w + 16 * tau + col;
        ((__hip_fp8_e4m3*)hs)[j] = __hip_fp8_e4m3(hold[tau]);
        outb[(size_t)t * (BB * HH) + j] = valid ? hnew : 0.f;
      }
      c0[tau] = n0[tau]; c1[tau] = n1[tau]; c2[tau] = n2[tau];
    }
    BARRIER_LDS();
  }
  if (lane < 16) {
    #pragma unroll
    for (int tau = 0; tau < 4; ++tau)
      hT[(size_t)b * HH + 64 * w + 16 * tau + col] = hold[tau];
  }
}

// ---------------------------------------------------------------------------
// ctx[b, h*256+d] = sum_l wsoft[l,b,h] * out1[l,b,d]
// ---------------------------------------------------------------------------
__global__ void ctx_kernel(
    const float* __restrict__ wsoft, const float* __restrict__ out1,
    float* __restrict__ ctx)
{
  int b = blockIdx.x >> 3, h = blockIdx.x & 7;
  int d = threadIdx.x;  // 256
  float acc = 0.f;
  for (int l = 0; l < LL; ++l) {
    float w = wsoft[((size_t)l * BB + b) * NHH + h];
    acc += w * out1[((size_t)l * BB + b) * HH + d];
  }
  ctx[(size_t)b * (NHH * HH) + h * HH + d] = acc;
}

// ---------------------------------------------------------------------------
// final MLP: z = selu([ctx, hT] @ Wf0.T + bf0); logits = z @ Wf1.T + bf1;
// out = log_softmax(logits)
// ---------------------------------------------------------------------------
__global__ __launch_bounds__(512) void final_kernel(
    const float* __restrict__ ctx, const float* __restrict__ hT,
    const float* __restrict__ Wf0,   // [168][2304]
    const float* __restrict__ bf0,
    const float* __restrict__ Wf1,   // [100][168]
    const float* __restrict__ bf1,
    float* __restrict__ outp)        // [B][100]
{
  int b = blockIdx.x;
  int tid = threadIdx.x;
  int wave = tid >> 6, lane = tid & 63;
  __shared__ float4 xs4[CLSIN / 4];
  __shared__ float zs[F1];
  __shared__ float ls[ETA];
  float* xs = (float*)xs4;
  for (int i = tid; i < NHH * HH; i += 512) xs[i] = ctx[(size_t)b * (NHH * HH) + i];
  if (tid < HH) xs[NHH * HH + tid] = hT[(size_t)b * HH + tid];
  __syncthreads();
  for (int r = wave; r < F1; r += 8) {
    const float4* wp = (const float4*)(Wf0 + (size_t)r * CLSIN);
    float acc = 0.f;
    #pragma unroll
    for (int i = 0; i < CLSIN / 4 / 64; ++i) {  // 9
      float4 w = wp[lane + 64 * i];
      float4 x = xs4[lane + 64 * i];
      acc += w.x * x.x + w.y * x.y + w.z * x.z + w.w * x.w;
    }
    #pragma unroll
    for (int off = 32; off > 0; off >>= 1) acc += __shfl_xor(acc, off, 64);
    if (lane == 0) {
      float x = acc + bf0[r];
      const float alpha = 1.6732632423543772f, scale = 1.0507009873554805f;
      zs[r] = scale * (x > 0.f ? x : alpha * (__expf(x) - 1.f));
    }
  }
  __syncthreads();
  for (int r = wave; r < ETA; r += 8) {
    float acc = 0.f;
    for (int k = lane; k < F1; k += 64) acc += Wf1[r * F1 + k] * zs[k];
    #pragma unroll
    for (int off = 32; off > 0; off >>= 1) acc += __shfl_xor(acc, off, 64);
    if (lane == 0) ls[r] = acc + bf1[r];
  }
  __syncthreads();
  if (wave == 0) {
    float v0 = (lane < ETA) ? ls[lane] : -1e30f;
    float v1 = (lane + 64 < ETA) ? ls[lane + 64] : -1e30f;
    float m = fmaxf(v0, v1);
    #pragma unroll
    for (int off = 32; off > 0; off >>= 1) m = fmaxf(m, __shfl_xor(m, off, 64));
    float s = __expf(v0 - m) + __expf(v1 - m);
    #pragma unroll
    for (int off = 32; off > 0; off >>= 1) s += __shfl_xor(s, off, 64);
    float lse = m + __logf(s);
    if (lane < ETA) outp[(size_t)b * ETA + lane] = v0 - lse;
    if (lane + 64 < ETA) outp[(size_t)b * ETA + lane + 64] = v1 - lse;
  }
}

extern "C" void kernel_launch(void* const* d_in, const int* in_sizes, int n_in,
                              void* d_out, int out_size, void* d_ws, size_t ws_size,
                              hipStream_t stream) {
  const int*   node  = (const int*)d_in[0];
  const float* ts    = (const float*)d_in[1];
  const int*   slen  = (const int*)d_in[2];
  const float* table = (const float*)d_in[3];
  const float* Wih0  = (const float*)d_in[4];
  const float* Whh0  = (const float*)d_in[5];
  const float* bih0  = (const float*)d_in[6];
  const float* bhh0  = (const float*)d_in[7];
  const float* Wih1  = (const float*)d_in[8];
  const float* Whh1  = (const float*)d_in[9];
  const float* bih1  = (const float*)d_in[10];
  const float* bhh1  = (const float*)d_in[11];
  const float* Wa0   = (const float*)d_in[12];
  const float* ba0   = (const float*)d_in[13];
  const float* Wa1   = (const float*)d_in[14];
  const float* ba1   = (const float*)d_in[15];
  const float* Wf0   = (const float*)d_in[16];
  const float* bf0   = (const float*)d_in[17];
  const float* Wf1   = (const float*)d_in[18];
  const float* bf1   = (const float*)d_in[19];

  char* ws = (char*)d_ws;
  size_t off = 0;
  auto alloc = [&](size_t n) { void* p = (void*)(ws + off); off += (n + 255) & ~(size_t)255; return p; };

  half2v* e_h2 = (half2v*)alloc((size_t)LL * BB * 64 * 4);
  float* U     = (float*)alloc((size_t)LL * BB * EE * 4);
  float* V     = (float*)alloc((size_t)LL * BB * EE * 4);
  float* gi    = (float*)alloc((size_t)LL * BB * G3 * 4);   // reused for both layers
  float* out0  = (float*)alloc((size_t)LL * BB * HH * 4);
  float* out1  = (float*)alloc((size_t)LL * BB * HH * 4);
  float* hTb   = (float*)alloc((size_t)BB * HH * 4);
  float* wpre  = (float*)alloc((size_t)LL * BB * NHH * 4);
  float* wsoft = (float*)alloc((size_t)LL * BB * NHH * 4);
  float* ctxb  = (float*)alloc((size_t)BB * NHH * HH * 4);
  half_t* Wa0Ta = (half_t*)alloc((size_t)128 * 128 * 2);
  half_t* Wa0Tb = (half_t*)alloc((size_t)128 * 128 * 2);
  half2v* Wih0T2 = (half2v*)alloc((size_t)65 * 768 * 4);
  half2v* Wih1T2 = (half2v*)alloc((size_t)128 * 768 * 4);
  __hip_fp8_e4m3* Whh0q = (__hip_fp8_e4m3*)alloc((size_t)G3 * HH);
  __hip_fp8_e4m3* Whh1q = (__hip_fp8_e4m3*)alloc((size_t)G3 * HH);
  if (off > ws_size) return;  // workspace too small: fail visibly

  const int prep_total = 16384 + 16384 + 65 * 768 + 128 * 768 + 196608 + 196608;
  prep_kernel<<<(prep_total + 255) / 256, 256, 0, stream>>>(
      Wa0, Wih0, Wih1, Whh0, Whh1, Wa0Ta, Wa0Tb, Wih0T2, Wih1T2, Whh0q, Whh1q);
  embed_uv_kernel<<<LL * BB, 128, 0, stream>>>(node, table, Wa0Ta, Wa0Tb, ba0, e_h2, U, V);
  attn_w_kernel<<<(LL / 4) * BB, 128, 0, stream>>>(U, V, Wa1, ba1, wpre);
  attn_softmax_kernel<<<BB * NHH, 128, 0, stream>>>(wpre, slen, wsoft);
  gi0_kernel<<<LL * BB / 8, 256, 0, stream>>>(e_h2, ts, Wih0T2, bih0, gi);
  gru_scan_kernel<<<BB, 256, 0, stream>>>(Whh0q, bhh0, gi, slen, out0, hTb);
  gi1_kernel<<<LL * BB / 8, 256, 0, stream>>>(out0, Wih1T2, bih1, gi);
  gru_scan_kernel<<<BB, 256, 0, stream>>>(Whh1q, bhh1, gi, slen, out1, hTb);
  ctx_kernel<<<BB * NHH, 256, 0, stream>>>(wsoft, out1, ctxb);
  final_kernel<<<BB, 512, 0, stream>>>(ctxb, hTb, Wf0, bf0, Wf1, bf1, (float*)d_out);
}

// Round 9
// 665.434 us; speedup vs baseline: 1.1834x; 1.0436x over previous
//
#include <hip/hip_runtime.h>
#include <hip/hip_bf16.h>
#include <hip/hip_fp8.h>

#define LL 128
#define BB 32
#define EE 128
#define HH 256
#define NHH 8
#define G3 768   // 3*H
#define IN0 130
#define ETA 100
#define F1 168
#define CLSIN 2304  // 8*256 + 256

typedef _Float16 half_t;
typedef __attribute__((ext_vector_type(2))) _Float16 half2v;
typedef __attribute__((ext_vector_type(4))) float floatx4;

#if defined(__has_builtin)
#if __has_builtin(__builtin_amdgcn_fdot2)
#define HAVE_FDOT2 1
#endif
#endif

__device__ __forceinline__ float fdot2f(half2v a, half2v b, float c) {
#ifdef HAVE_FDOT2
  return __builtin_amdgcn_fdot2(a, b, c, false);
#else
  return c + (float)a.x * (float)b.x + (float)a.y * (float)b.y;
#endif
}

// LDS-only barrier: no vmcnt drain — weight prefetch loads stay in flight
// across the per-step barrier (cp.async-style pipelining).
#define BARRIER_LDS() __asm__ volatile("s_waitcnt lgkmcnt(0)\n\ts_barrier" ::: "memory")

__device__ __forceinline__ float sigmoidf_(float x) { return 1.0f / (1.0f + __expf(-x)); }
__device__ __forceinline__ float tanhf_(float x) { return 1.0f - 2.0f / (__expf(2.0f * x) + 1.0f); }

// ---------------------------------------------------------------------------
// prep: weight repack. Wa0/Wih -> f16. Whh -> fp8 e4m3 (absmax 0.031 verified r8).
// ---------------------------------------------------------------------------
__global__ void prep_kernel(
    const float* __restrict__ Wa0, const float* __restrict__ Wih0,
    const float* __restrict__ Wih1, const float* __restrict__ Whh0,
    const float* __restrict__ Whh1,
    half_t* __restrict__ Wa0Ta, half_t* __restrict__ Wa0Tb,
    half2v* __restrict__ Wih0T2, half2v* __restrict__ Wih1T2,
    __hip_fp8_e4m3* __restrict__ Whh0q, __hip_fp8_e4m3* __restrict__ Whh1q)
{
  int idx = blockIdx.x * blockDim.x + threadIdx.x;
  const int n1 = 16384, n2 = 16384, n3 = 65 * 768, n4 = 128 * 768, n5 = 196608;
  if (idx < n1) {
    int d = idx >> 7, k = idx & 127;
    Wa0Ta[idx] = (half_t)Wa0[k * 256 + d];
  } else if ((idx -= n1) < n2) {
    int d = idx >> 7, k = idx & 127;
    Wa0Tb[idx] = (half_t)Wa0[k * 256 + 128 + d];
  } else if ((idx -= n2) < n3) {
    int d2 = idx / 768, r = idx % 768;
    half2v w; w.x = (half_t)Wih0[r * IN0 + 2 * d2]; w.y = (half_t)Wih0[r * IN0 + 2 * d2 + 1];
    Wih0T2[idx] = w;
  } else if ((idx -= n3) < n4) {
    int d2 = idx / 768, r = idx % 768;
    half2v w; w.x = (half_t)Wih1[r * HH + 2 * d2]; w.y = (half_t)Wih1[r * HH + 2 * d2 + 1];
    Wih1T2[idx] = w;
  } else if ((idx -= n4) < n5) {
    Whh0q[idx] = __hip_fp8_e4m3(Whh0[idx]);
  } else if ((idx -= n5) < n5) {
    Whh1q[idx] = __hip_fp8_e4m3(Whh1[idx]);
  }
}

// ---------------------------------------------------------------------------
// embed gather + U/V factors of the pairwise attention
// ---------------------------------------------------------------------------
__global__ void embed_uv_kernel(
    const int* __restrict__ node,             // [L*B]
    const float* __restrict__ table,          // [20001][128]
    const half_t* __restrict__ Wa0Ta,         // [128 d][128 k]
    const half_t* __restrict__ Wa0Tb,
    const float* __restrict__ ba0,            // [128]
    half2v* __restrict__ e_h2,                // [L*B][64]
    float* __restrict__ U,
    float* __restrict__ V)
{
  int lb = blockIdx.x;
  int k = threadIdx.x;  // 128
  __shared__ float es[EE];
  int n = node[lb];
  float ev = table[(size_t)n * EE + k];
  es[k] = ev;
  __syncthreads();
  if (k < 64) {
    half2v p; p.x = (half_t)es[2 * k]; p.y = (half_t)es[2 * k + 1];
    e_h2[(size_t)lb * 64 + k] = p;
  }
  float u = 0.f, v = ba0[k];
  #pragma unroll 8
  for (int d = 0; d < EE; ++d) {
    float x = es[d];
    u += (float)Wa0Ta[d * EE + k] * x;
    v += (float)Wa0Tb[d * EE + k] * x;
  }
  U[(size_t)lb * EE + k] = u;
  V[(size_t)lb * EE + k] = v;
}

// ---------------------------------------------------------------------------
// w_pre[i,b,h] = sum_j sum_k Wa1[h,k] * relu(U[j,b,k]+V[i,b,k]) + L*ba1[h]
// ---------------------------------------------------------------------------
__global__ __launch_bounds__(128) void attn_w_kernel(
    const float* __restrict__ U, const float* __restrict__ V,
    const float* __restrict__ Wa1,  // [8][128]
    const float* __restrict__ ba1,  // [8]
    float* __restrict__ wpre)       // [L][B][8]
{
  int ig = blockIdx.x >> 5;
  int b = blockIdx.x & 31;
  int i0 = ig * 4;
  int k = threadIdx.x;  // 128
  float vk[4];
  #pragma unroll
  for (int ii = 0; ii < 4; ++ii) vk[ii] = V[((size_t)(i0 + ii) * BB + b) * EE + k];
  float wa[NHH], acc[4][NHH];
  #pragma unroll
  for (int h = 0; h < NHH; ++h) wa[h] = Wa1[h * EE + k];
  #pragma unroll
  for (int ii = 0; ii < 4; ++ii)
    #pragma unroll
    for (int h = 0; h < NHH; ++h) acc[ii][h] = 0.f;
  for (int j = 0; j < LL; ++j) {
    float u = U[((size_t)j * BB + b) * EE + k];
    #pragma unroll
    for (int ii = 0; ii < 4; ++ii) {
      float tv = fmaxf(u + vk[ii], 0.f);
      #pragma unroll
      for (int h = 0; h < NHH; ++h) acc[ii][h] += wa[h] * tv;
    }
  }
  __shared__ float part[2][32];
  int wave = k >> 6, lane = k & 63;
  #pragma unroll
  for (int ii = 0; ii < 4; ++ii)
    #pragma unroll
    for (int h = 0; h < NHH; ++h) {
      float a = acc[ii][h];
      #pragma unroll
      for (int off = 32; off > 0; off >>= 1) a += __shfl_xor(a, off, 64);
      if (lane == 0) part[wave][ii * 8 + h] = a;
    }
  __syncthreads();
  if (k < 32) {
    int ii = k >> 3, h = k & 7;
    float w = part[0][k] + part[1][k] + (float)LL * ba1[h];
    wpre[((size_t)(i0 + ii) * BB + b) * NHH + h] = w;
  }
}

// softmax over l of (w * mask): masked entries become 0 and STAY in the softmax
__global__ void attn_softmax_kernel(
    const float* __restrict__ wpre, const int* __restrict__ slen,
    float* __restrict__ wsoft)
{
  int b = blockIdx.x >> 3;
  int h = blockIdx.x & 7;
  int l = threadIdx.x;  // 128
  int len = slen[b];
  float x = wpre[((size_t)l * BB + b) * NHH + h];
  float xv = (l < len) ? x : 0.f;
  float m = xv;
  #pragma unroll
  for (int off = 32; off > 0; off >>= 1) m = fmaxf(m, __shfl_xor(m, off, 64));
  __shared__ float sm[2], ss[2];
  int wave = l >> 6;
  if ((l & 63) == 0) sm[wave] = m;
  __syncthreads();
  m = fmaxf(sm[0], sm[1]);
  float e = __expf(xv - m);
  float s = e;
  #pragma unroll
  for (int off = 32; off > 0; off >>= 1) s += __shfl_xor(s, off, 64);
  if ((l & 63) == 0) ss[wave] = s;
  __syncthreads();
  s = ss[0] + ss[1];
  wsoft[((size_t)l * BB + b) * NHH + h] = e / s;
}

// ---------------------------------------------------------------------------
// gi0: [e, ts] @ Wih0.T + bih0, 8 lb per block, v_dot2 on packed pairs
// ---------------------------------------------------------------------------
__global__ __launch_bounds__(256) void gi0_kernel(
    const half2v* __restrict__ e_h2, const float* __restrict__ ts,
    const half2v* __restrict__ W2,   // [65][768]
    const float* __restrict__ bih,
    float* __restrict__ gi)
{
  int lb0 = blockIdx.x * 8;
  int tid = threadIdx.x;  // 256
  __shared__ half2v xs2[8][66];
  for (int idx = tid; idx < 512; idx += 256) {
    int q = idx >> 6, d2 = idx & 63;
    xs2[q][d2] = e_h2[(size_t)(lb0 + q) * 64 + d2];
  }
  if (tid < 8) {
    half2v t2; t2.x = (half_t)ts[(lb0 + tid) * 2]; t2.y = (half_t)ts[(lb0 + tid) * 2 + 1];
    xs2[tid][64] = t2;
  }
  __syncthreads();
  float acc[8][3];
  #pragma unroll
  for (int q = 0; q < 8; ++q) { acc[q][0] = 0.f; acc[q][1] = 0.f; acc[q][2] = 0.f; }
  for (int d2 = 0; d2 < 65; ++d2) {
    half2v w0 = W2[d2 * 768 + tid];
    half2v w1 = W2[d2 * 768 + 256 + tid];
    half2v w2 = W2[d2 * 768 + 512 + tid];
    #pragma unroll
    for (int q = 0; q < 8; ++q) {
      half2v x = xs2[q][d2];
      acc[q][0] = fdot2f(w0, x, acc[q][0]);
      acc[q][1] = fdot2f(w1, x, acc[q][1]);
      acc[q][2] = fdot2f(w2, x, acc[q][2]);
    }
  }
  float b0 = bih[tid], b1 = bih[256 + tid], b2 = bih[512 + tid];
  #pragma unroll
  for (int q = 0; q < 8; ++q) {
    float* gp = gi + (size_t)(lb0 + q) * G3;
    gp[tid] = acc[q][0] + b0; gp[256 + tid] = acc[q][1] + b1; gp[512 + tid] = acc[q][2] + b2;
  }
}

// ---------------------------------------------------------------------------
// gi1: out0 @ Wih1.T + bih1, 8 lb per block
// ---------------------------------------------------------------------------
__global__ __launch_bounds__(256) void gi1_kernel(
    const float* __restrict__ out0,  // [L*B][256]
    const half2v* __restrict__ W2,   // [128][768]
    const float* __restrict__ bih,
    float* __restrict__ gi)
{
  int lb0 = blockIdx.x * 8;
  int tid = threadIdx.x;  // 256
  __shared__ half2v xs2[8][128];
  for (int idx = tid; idx < 1024; idx += 256) {
    int q = idx >> 7, d2 = idx & 127;
    float2 v = ((const float2*)(out0 + (size_t)(lb0 + q) * HH))[d2];
    half2v x; x.x = (half_t)v.x; x.y = (half_t)v.y;
    xs2[q][d2] = x;
  }
  __syncthreads();
  float acc[8][3];
  #pragma unroll
  for (int q = 0; q < 8; ++q) { acc[q][0] = 0.f; acc[q][1] = 0.f; acc[q][2] = 0.f; }
  for (int d2 = 0; d2 < 128; ++d2) {
    half2v w0 = W2[d2 * 768 + tid];
    half2v w1 = W2[d2 * 768 + 256 + tid];
    half2v w2 = W2[d2 * 768 + 512 + tid];
    #pragma unroll
    for (int q = 0; q < 8; ++q) {
      half2v x = xs2[q][d2];
      acc[q][0] = fdot2f(w0, x, acc[q][0]);
      acc[q][1] = fdot2f(w1, x, acc[q][1]);
      acc[q][2] = fdot2f(w2, x, acc[q][2]);
    }
  }
  float b0 = bih[tid], b1 = bih[256 + tid], b2 = bih[512 + tid];
  #pragma unroll
  for (int q = 0; q < 8; ++q) {
    float* gp = gi + (size_t)(lb0 + q) * G3;
    gp[tid] = acc[q][0] + b0; gp[256 + tid] = acc[q][1] + b1; gp[512 + tid] = acc[q][2] + b2;
  }
}

// ---------------------------------------------------------------------------
// GRU scan, STREAMING fp8-MFMA. Residency is unobtainable (r3-r8); instead
// stream the 192 KB fp8 Whh from L2 every step (floor ~1465 cyc/step vs
// r5's 2930 f16) and hide it with a 4-group software pipeline: group g+1's
// global loads issue while group g's MFMAs run; next-step group-0 loads
// stay in flight across the (single, LDS-only) barrier. All weight values
// are short-lived within one iteration — nothing for the allocator to spill.
// Tile layout identical to r7/r8 (verified absmax 0.0 / 0.031).
// ---------------------------------------------------------------------------
__global__ __launch_bounds__(256, 1) void gru_scan_kernel(
    const __hip_fp8_e4m3* __restrict__ Whhq, // [768][256] fp8
    const float* __restrict__ bhh,           // [768]
    const float* __restrict__ gi,            // [L][B][768]
    const int* __restrict__ slen,            // [B]
    float* __restrict__ out,                 // [L][B][256]
    float* __restrict__ hT)                  // [B][256]
{
  const int b = blockIdx.x;
  const int tid = threadIdx.x;  // 256
  const int w = tid >> 6;
  const int lane = tid & 63;
  const int col = lane & 15;
  const int quad = lane >> 4;
  __shared__ __align__(8) unsigned char hs[2][HH];  // double-buffered fp8 h

  const unsigned char* Wq = (const unsigned char*)Whhq;
  // row(tt=g3*4+tau) = 256*g3 + 64*w + 16*tau + col; byte = row*256+32*ks+8*quad
  const unsigned char* base = Wq + (size_t)(64 * w + col) * HH + 8 * quad;
#define TOFF(tt) (((tt) >> 2) * 65536 + ((tt) & 3) * 4096)

  uint2 wbuf[4][24];  // 4 groups x 3 tiles x 8 ks; <=2 groups in flight
#define LOADG(g)                                                            \
  {                                                                         \
    _Pragma("unroll")                                                       \
    for (int i = 0; i < 24; ++i) {                                          \
      int tt = (g) * 3 + (i >> 3);                                          \
      wbuf[g][i] = *(const uint2*)(base + TOFF(tt) + (i & 7) * 32);         \
    }                                                                       \
  }
#define MFMAG(g)                                                            \
  {                                                                         \
    _Pragma("unroll")                                                       \
    for (int ks = 0; ks < 8; ++ks) {                                        \
      _Pragma("unroll")                                                     \
      for (int j = 0; j < 3; ++j)                                           \
        acc[(g) * 3 + j] = __builtin_amdgcn_mfma_f32_16x16x32_fp8_fp8(      \
            ha[ks], __builtin_bit_cast(long, wbuf[g][j * 8 + ks]),          \
            acc[(g) * 3 + j], 0, 0, 0);                                     \
    }                                                                       \
  }

  const int len = slen[b];
  float hold[4], br[4], bz[4], bn[4];
  #pragma unroll
  for (int tau = 0; tau < 4; ++tau) {
    int j = 64 * w + 16 * tau + col;
    hold[tau] = 0.f;
    br[tau] = bhh[j]; bz[tau] = bhh[256 + j]; bn[tau] = bhh[512 + j];
  }
  if (tid < 128) ((unsigned int*)hs)[tid] = 0u;  // zero both buffers
  __syncthreads();

  const float* gib = gi + (size_t)b * G3;
  float* outb = out + (size_t)b * HH;

  LOADG(0)  // prologue

  #pragma unroll 1
  for (int t = 0; t < LL; ++t) {
    const unsigned char* hr = hs[t & 1];
    unsigned char* hw = (unsigned char*)hs[(t & 1) ^ 1];
    LOADG(1)
    // gi for this step (latency hides under the MFMA/stream phase)
    const float* gp = gib + (size_t)t * (BB * G3);
    float c0[4], c1[4], c2[4];
    #pragma unroll
    for (int tau = 0; tau < 4; ++tau) {
      int j = 64 * w + 16 * tau + col;
      c0[tau] = gp[j]; c1[tau] = gp[256 + j]; c2[tau] = gp[512 + j];
    }
    // h fragments from LDS (8B each, A-operand replicated over M)
    long ha[8];
    #pragma unroll
    for (int ks = 0; ks < 8; ++ks)
      ha[ks] = __builtin_bit_cast(long, *(const uint2*)(hr + 32 * ks + 8 * quad));
    floatx4 acc[12];
    #pragma unroll
    for (int i = 0; i < 12; ++i) { floatx4 z = {0.f, 0.f, 0.f, 0.f}; acc[i] = z; }
    MFMAG(0)
    LOADG(2)
    MFMAG(1)
    LOADG(3)
    MFMAG(2)
    LOADG(0)  // prefetch next step's group 0 — stays in flight across barrier
    MFMAG(3)
    bool valid = t < len;
    #pragma unroll
    for (int tau = 0; tau < 4; ++tau) {
      float r_ = sigmoidf_(c0[tau] + acc[tau].x + br[tau]);
      float z_ = sigmoidf_(c1[tau] + acc[4 + tau].x + bz[tau]);
      float nn = tanhf_(c2[tau] + r_ * (acc[8 + tau].x + bn[tau]));
      float hnew = (1.f - z_) * nn + z_ * hold[tau];
      hold[tau] = valid ? hnew : hold[tau];
      if (lane < 16) {
        int j = 64 * w + 16 * tau + col;
        ((__hip_fp8_e4m3*)hw)[j] = __hip_fp8_e4m3(hold[tau]);
        outb[(size_t)t * (BB * HH) + j] = valid ? hnew : 0.f;
      }
    }
    BARRIER_LDS();  // single barrier: writes went to the other h buffer
  }
  if (lane < 16) {
    #pragma unroll
    for (int tau = 0; tau < 4; ++tau)
      hT[(size_t)b * HH + 64 * w + 16 * tau + col] = hold[tau];
  }
#undef LOADG
#undef MFMAG
#undef TOFF
}

// ---------------------------------------------------------------------------
// fused ctx + final MLP: ctx[h,d] = sum_l wsoft[l,b,h]*out1[l,b,d];
// z = selu([ctx,hT]@Wf0.T+bf0); logits = z@Wf1.T+bf1; out = log_softmax.
// ---------------------------------------------------------------------------
__global__ __launch_bounds__(512) void final_kernel(
    const float* __restrict__ wsoft,  // [L][B][8]
    const float* __restrict__ out1,   // [L][B][256]
    const float* __restrict__ hT,
    const float* __restrict__ Wf0,    // [168][2304]
    const float* __restrict__ bf0,
    const float* __restrict__ Wf1,    // [100][168]
    const float* __restrict__ bf1,
    float* __restrict__ outp)         // [B][100]
{
  int b = blockIdx.x;
  int tid = threadIdx.x;
  int wave = tid >> 6, lane = tid & 63;
  __shared__ float4 xs4[CLSIN / 4];
  __shared__ float ws[LL][NHH];
  __shared__ float part[NHH * HH];
  __shared__ float zs[F1];
  __shared__ float ls[ETA];
  float* xs = (float*)xs4;
  for (int i = tid; i < LL * NHH; i += 512) {
    int l = i >> 3, h = i & 7;
    ws[l][h] = wsoft[((size_t)l * BB + b) * NHH + h];
  }
  if (tid < HH) xs[NHH * HH + tid] = hT[(size_t)b * HH + tid];
  __syncthreads();
  {
    int d = tid & 255, lh = tid >> 8;
    float ac[NHH] = {0.f, 0.f, 0.f, 0.f, 0.f, 0.f, 0.f, 0.f};
    for (int l = 64 * lh; l < 64 * (lh + 1); ++l) {
      float x = out1[((size_t)l * BB + b) * HH + d];
      #pragma unroll
      for (int h = 0; h < NHH; ++h) ac[h] += ws[l][h] * x;
    }
    if (lh) {
      #pragma unroll
      for (int h = 0; h < NHH; ++h) part[h * HH + d] = ac[h];
    }
    __syncthreads();
    if (!lh) {
      #pragma unroll
      for (int h = 0; h < NHH; ++h) xs[h * HH + d] = ac[h] + part[h * HH + d];
    }
    __syncthreads();
  }
  for (int r = wave; r < F1; r += 8) {
    const float4* wp = (const float4*)(Wf0 + (size_t)r * CLSIN);
    float acc = 0.f;
    #pragma unroll
    for (int i = 0; i < CLSIN / 4 / 64; ++i) {  // 9
      float4 w = wp[lane + 64 * i];
      float4 x = xs4[lane + 64 * i];
      acc += w.x * x.x + w.y * x.y + w.z * x.z + w.w * x.w;
    }
    #pragma unroll
    for (int off = 32; off > 0; off >>= 1) acc += __shfl_xor(acc, off, 64);
    if (lane == 0) {
      float x = acc + bf0[r];
      const float alpha = 1.6732632423543772f, scale = 1.0507009873554805f;
      zs[r] = scale * (x > 0.f ? x : alpha * (__expf(x) - 1.f));
    }
  }
  __syncthreads();
  for (int r = wave; r < ETA; r += 8) {
    float acc = 0.f;
    for (int k = lane; k < F1; k += 64) acc += Wf1[r * F1 + k] * zs[k];
    #pragma unroll
    for (int off = 32; off > 0; off >>= 1) acc += __shfl_xor(acc, off, 64);
    if (lane == 0) ls[r] = acc + bf1[r];
  }
  __syncthreads();
  if (wave == 0) {
    float v0 = (lane < ETA) ? ls[lane] : -1e30f;
    float v1 = (lane + 64 < ETA) ? ls[lane + 64] : -1e30f;
    float m = fmaxf(v0, v1);
    #pragma unroll
    for (int off = 32; off > 0; off >>= 1) m = fmaxf(m, __shfl_xor(m, off, 64));
    float s = __expf(v0 - m) + __expf(v1 - m);
    #pragma unroll
    for (int off = 32; off > 0; off >>= 1) s += __shfl_xor(s, off, 64);
    float lse = m + __logf(s);
    if (lane < ETA) outp[(size_t)b * ETA + lane] = v0 - lse;
    if (lane + 64 < ETA) outp[(size_t)b * ETA + lane + 64] = v1 - lse;
  }
}

extern "C" void kernel_launch(void* const* d_in, const int* in_sizes, int n_in,
                              void* d_out, int out_size, void* d_ws, size_t ws_size,
                              hipStream_t stream) {
  const int*   node  = (const int*)d_in[0];
  const float* ts    = (const float*)d_in[1];
  const int*   slen  = (const int*)d_in[2];
  const float* table = (const float*)d_in[3];
  const float* Wih0  = (const float*)d_in[4];
  const float* Whh0  = (const float*)d_in[5];
  const float* bih0  = (const float*)d_in[6];
  const float* bhh0  = (const float*)d_in[7];
  const float* Wih1  = (const float*)d_in[8];
  const float* Whh1  = (const float*)d_in[9];
  const float* bih1  = (const float*)d_in[10];
  const float* bhh1  = (const float*)d_in[11];
  const float* Wa0   = (const float*)d_in[12];
  const float* ba0   = (const float*)d_in[13];
  const float* Wa1   = (const float*)d_in[14];
  const float* ba1   = (const float*)d_in[15];
  const float* Wf0   = (const float*)d_in[16];
  const float* bf0   = (const float*)d_in[17];
  const float* Wf1   = (const float*)d_in[18];
  const float* bf1   = (const float*)d_in[19];

  char* ws = (char*)d_ws;
  size_t off = 0;
  auto alloc = [&](size_t n) { void* p = (void*)(ws + off); off += (n + 255) & ~(size_t)255; return p; };

  half2v* e_h2 = (half2v*)alloc((size_t)LL * BB * 64 * 4);
  float* U     = (float*)alloc((size_t)LL * BB * EE * 4);
  float* V     = (float*)alloc((size_t)LL * BB * EE * 4);
  float* gi    = (float*)alloc((size_t)LL * BB * G3 * 4);   // reused for both layers
  float* out0  = (float*)alloc((size_t)LL * BB * HH * 4);
  float* out1  = (float*)alloc((size_t)LL * BB * HH * 4);
  float* hTb   = (float*)alloc((size_t)BB * HH * 4);
  float* wpre  = (float*)alloc((size_t)LL * BB * NHH * 4);
  float* wsoft = (float*)alloc((size_t)LL * BB * NHH * 4);
  half_t* Wa0Ta = (half_t*)alloc((size_t)128 * 128 * 2);
  half_t* Wa0Tb = (half_t*)alloc((size_t)128 * 128 * 2);
  half2v* Wih0T2 = (half2v*)alloc((size_t)65 * 768 * 4);
  half2v* Wih1T2 = (half2v*)alloc((size_t)128 * 768 * 4);
  __hip_fp8_e4m3* Whh0q = (__hip_fp8_e4m3*)alloc((size_t)G3 * HH);
  __hip_fp8_e4m3* Whh1q = (__hip_fp8_e4m3*)alloc((size_t)G3 * HH);
  if (off > ws_size) return;  // workspace too small: fail visibly

  const int prep_total = 16384 + 16384 + 65 * 768 + 128 * 768 + 196608 + 196608;
  prep_kernel<<<(prep_total + 255) / 256, 256, 0, stream>>>(
      Wa0, Wih0, Wih1, Whh0, Whh1, Wa0Ta, Wa0Tb, Wih0T2, Wih1T2, Whh0q, Whh1q);
  embed_uv_kernel<<<LL * BB, 128, 0, stream>>>(node, table, Wa0Ta, Wa0Tb, ba0, e_h2, U, V);
  attn_w_kernel<<<(LL / 4) * BB, 128, 0, stream>>>(U, V, Wa1, ba1, wpre);
  attn_softmax_kernel<<<BB * NHH, 128, 0, stream>>>(wpre, slen, wsoft);
  gi0_kernel<<<LL * BB / 8, 256, 0, stream>>>(e_h2, ts, Wih0T2, bih0, gi);
  gru_scan_kernel<<<BB, 256, 0, stream>>>(Whh0q, bhh0, gi, slen, out0, hTb);
  gi1_kernel<<<LL * BB / 8, 256, 0, stream>>>(out0, Wih1T2, bih1, gi);
  gru_scan_kernel<<<BB, 256, 0, stream>>>(Whh1q, bhh1, gi, slen, out1, hTb);
  final_kernel<<<BB, 512, 0, stream>>>(wsoft, out1, hTb, Wf0, bf0, Wf1, bf1, (float*)d_out);
}